// Round 2
// baseline (502.993 us; speedup 1.0000x reference)
//
#include <hip/hip_runtime.h>
#include <stdint.h>

// N=50000 nodes, E=600000 edges, D=128.
#define DIM 128

typedef __attribute__((ext_vector_type(8))) short bf16x8;
typedef __attribute__((ext_vector_type(4))) float floatx4;

__device__ __forceinline__ float bf2f(unsigned short u) {
    union { unsigned int i; float f; } v; v.i = ((unsigned int)u) << 16; return v.f;
}
__device__ __forceinline__ unsigned short f2bf(float f) {
    union { float f; unsigned int i; } v; v.f = f;
    unsigned int r = (v.i + 0x7FFFu + ((v.i >> 16) & 1u)) >> 16;
    return (unsigned short)r;
}

// ---- dtype detection ---------------------------------------------------
// Low ushort of each 32b word read as bf16: sane (|x|<1e4) iff buffer is
// really bf16; if fp32, it's random mantissa bits -> ~45% huge/NaN.
// flag: 1 = inputs are fp32, 0 = inputs are bf16.
__global__ void detect_kernel(const unsigned int* __restrict__ w32, int* __restrict__ flag) {
    int t = threadIdx.x;  // 64 threads
    unsigned int v = w32[t];
    float f = bf2f((unsigned short)(v & 0xffffu));
    int bad = !(fabsf(f) < 1e4f);   // catches NaN too
    unsigned long long m = __ballot(bad);
    if (t == 0) *flag = (__popcll(m) > 16) ? 1 : 0;
}

// Canonicalize a float tensor (fp32 or bf16 per flag) to bf16.
__global__ void convert_kernel(const void* __restrict__ src, unsigned short* __restrict__ dst,
                               int n, const int* __restrict__ flag) {
    int i = blockIdx.x * 256 + threadIdx.x;
    if (i >= n) return;
    if (*flag) dst[i] = f2bf(((const float*)src)[i]);
    else       dst[i] = ((const unsigned short*)src)[i];
}

// ---- CSR build ---------------------------------------------------------

__global__ void hist_kernel(const int* __restrict__ dst, int* __restrict__ cnt, int E) {
    int e = blockIdx.x * 256 + threadIdx.x;
    if (e < E) atomicAdd(&cnt[dst[e]], 1);
}

__global__ __launch_bounds__(1024) void scan_kernel(int* __restrict__ cnt,
                                                    int* __restrict__ row_ptr, int N) {
    __shared__ int tmp[1024];
    int t = threadIdx.x;
    int chunk = (N + 1023) / 1024;
    int beg = t * chunk;
    int end = min(beg + chunk, N);
    int s = 0;
    for (int i = beg; i < end; ++i) s += cnt[i];
    tmp[t] = s;
    __syncthreads();
    for (int off = 1; off < 1024; off <<= 1) {
        int v = (t >= off) ? tmp[t - off] : 0;
        __syncthreads();
        tmp[t] += v;
        __syncthreads();
    }
    int run = (t == 0) ? 0 : tmp[t - 1];
    if (beg < N) {
        for (int i = beg; i < end; ++i) {
            int c = cnt[i];
            row_ptr[i] = run;
            cnt[i] = run;      // cursor = row start
            run += c;
        }
        if (end == N) row_ptr[N] = run;
    }
}

__global__ void scatter_kernel(const int* __restrict__ src, const int* __restrict__ dst,
                               const void* __restrict__ w_any,
                               int* __restrict__ cursor,
                               int* __restrict__ s_src, float* __restrict__ s_w,
                               const int* __restrict__ flag, int E) {
    int e = blockIdx.x * 256 + threadIdx.x;
    if (e >= E) return;
    float wv = (*flag) ? ((const float*)w_any)[e]
                       : bf2f(((const unsigned short*)w_any)[e]);
    int d = dst[e];
    int pos = atomicAdd(&cursor[d], 1);
    s_src[pos] = src[e];
    s_w[pos] = wv;
}

// ---- h0 = emb[node_ids], canonicalized to bf16 -------------------------

__global__ void gather_h0(const int* __restrict__ ids, const void* __restrict__ emb,
                          unsigned int* __restrict__ h032,
                          const int* __restrict__ flag, int total) {
    int t = blockIdx.x * 256 + threadIdx.x;
    if (t >= total) return;
    int n = t >> 6;           // 64 uints (=128 bf16) per row
    int f = t & 63;
    int id = ids[n];
    unsigned int o;
    if (*flag) {
        const float* e = (const float*)emb + (size_t)id * DIM + f * 2;
        o = ((unsigned int)f2bf(e[1]) << 16) | (unsigned int)f2bf(e[0]);
    } else {
        o = ((const unsigned int*)emb)[(size_t)id * 64 + f];
    }
    h032[t] = o;
}

// ---- neighbor mean: one wave per node ----------------------------------

__global__ __launch_bounds__(256) void agg_kernel(const unsigned int* __restrict__ h32,
                                                  const int* __restrict__ row_ptr,
                                                  const int* __restrict__ s_src,
                                                  const float* __restrict__ s_w,
                                                  unsigned int* __restrict__ out32,
                                                  int N, int E) {
    int node = blockIdx.x * 4 + (threadIdx.x >> 6);
    int lane = threadIdx.x & 63;
    if (node >= N) return;
    int beg = max(row_ptr[node], 0);
    int end = min(row_ptr[node + 1], E);
    float a0 = 0.f, a1 = 0.f;
    for (int e = beg; e < end; ++e) {
        int s = s_src[e];
        if ((unsigned)s >= (unsigned)N) continue;   // safety: finite-wrong, not NaN
        float w = s_w[e];
        unsigned int v = h32[(size_t)s * 64 + lane];
        a0 += w * bf2f((unsigned short)(v & 0xffffu));
        a1 += w * bf2f((unsigned short)(v >> 16));
    }
    float inv = (end > beg) ? 1.0f / (float)(end - beg) : 0.f;
    a0 *= inv; a1 *= inv;
    unsigned int o = ((unsigned int)f2bf(a1) << 16) | (unsigned int)f2bf(a0);
    out32[(size_t)node * 64 + lane] = o;
}

// ---- fused SAGE linear: out = h @ Wself^T + b + neigh @ Wneigh^T (+relu)
// MFMA 16x16x32 bf16. Block = 4 waves; wave computes 16 rows x 128 cols.
// A frag: lane holds A[m=lane&15][k=quad*8+j]; B frag: W[n=lane&15][k=quad*8+j]
// C/D: D[row=quad*4+r][col=lane&15]

__global__ __launch_bounds__(256) void gemm_layer(const unsigned short* __restrict__ A0,
                                                  const unsigned short* __restrict__ A1,
                                                  const unsigned short* __restrict__ W0,
                                                  const unsigned short* __restrict__ W1,
                                                  const unsigned short* __restrict__ bias,
                                                  void* __restrict__ out,
                                                  int n_rows, int relu, int is_final,
                                                  const int* __restrict__ flag) {
    int wave = threadIdx.x >> 6;
    int lane = threadIdx.x & 63;
    int quad = lane >> 4;
    int l16  = lane & 15;
    int m_base = blockIdx.x * 64 + wave * 16;
    int fp32_out = is_final ? *flag : 0;

    floatx4 acc[8];
#pragma unroll
    for (int c = 0; c < 8; ++c) acc[c] = (floatx4){0.f, 0.f, 0.f, 0.f};

    int arow = m_base + l16;
    if (arow >= n_rows) arow = n_rows - 1;   // clamp; stores are guarded
    const unsigned short* Ar0 = A0 + (size_t)arow * DIM;
    const unsigned short* Ar1 = A1 + (size_t)arow * DIM;

#pragma unroll
    for (int ks = 0; ks < 4; ++ks) {
        int k0 = ks * 32 + quad * 8;
        bf16x8 a = *(const bf16x8*)(Ar0 + k0);
#pragma unroll
        for (int c = 0; c < 8; ++c) {
            bf16x8 b = *(const bf16x8*)(W0 + (size_t)(c * 16 + l16) * DIM + k0);
            acc[c] = __builtin_amdgcn_mfma_f32_16x16x32_bf16(a, b, acc[c], 0, 0, 0);
        }
    }
#pragma unroll
    for (int ks = 0; ks < 4; ++ks) {
        int k0 = ks * 32 + quad * 8;
        bf16x8 a = *(const bf16x8*)(Ar1 + k0);
#pragma unroll
        for (int c = 0; c < 8; ++c) {
            bf16x8 b = *(const bf16x8*)(W1 + (size_t)(c * 16 + l16) * DIM + k0);
            acc[c] = __builtin_amdgcn_mfma_f32_16x16x32_bf16(a, b, acc[c], 0, 0, 0);
        }
    }

#pragma unroll
    for (int c = 0; c < 8; ++c) {
        int col = c * 16 + l16;
        float bv = bf2f(bias[col]);
#pragma unroll
        for (int r = 0; r < 4; ++r) {
            int row = m_base + quad * 4 + r;
            if (row < n_rows) {
                float v = acc[c][r] + bv;
                if (relu) v = fmaxf(v, 0.f);
                size_t idx = (size_t)row * DIM + col;
                if (fp32_out) ((float*)out)[idx] = v;
                else          ((unsigned short*)out)[idx] = f2bf(v);
            }
        }
    }
}

// ---- launch ------------------------------------------------------------

extern "C" void kernel_launch(void* const* d_in, const int* in_sizes, int n_in,
                              void* d_out, int out_size, void* d_ws, size_t ws_size,
                              hipStream_t stream) {
    const int* node_ids = (const int*)d_in[0];
    const int* edge_src = (const int*)d_in[1];
    const int* edge_dst = (const int*)d_in[2];
    const void* edge_w  = d_in[3];
    const void* emb     = d_in[4];
    const void* Ws1     = d_in[5];
    const void* Wn1     = d_in[6];
    const void* b1      = d_in[7];
    const void* Ws2     = d_in[8];
    const void* Wn2     = d_in[9];
    const void* b2      = d_in[10];

    const int N = in_sizes[0];
    const int E = in_sizes[1];

    char* w = (char*)d_ws;
    auto alloc = [&](size_t bytes) {
        char* p = w;
        w += (bytes + 255) & ~(size_t)255;
        return p;
    };
    int* flag           = (int*)alloc(4);
    int* row_ptr        = (int*)alloc((size_t)(N + 1) * 4);
    int* cnt            = (int*)alloc((size_t)N * 4);
    unsigned short* Ws1c = (unsigned short*)alloc((size_t)DIM * DIM * 2);
    unsigned short* Wn1c = (unsigned short*)alloc((size_t)DIM * DIM * 2);
    unsigned short* Ws2c = (unsigned short*)alloc((size_t)DIM * DIM * 2);
    unsigned short* Wn2c = (unsigned short*)alloc((size_t)DIM * DIM * 2);
    unsigned short* b1c  = (unsigned short*)alloc((size_t)DIM * 2);
    unsigned short* b2c  = (unsigned short*)alloc((size_t)DIM * 2);
    int* s_src          = (int*)alloc((size_t)E * 4);
    float* s_w          = (float*)alloc((size_t)E * 4);
    unsigned short* h0  = (unsigned short*)alloc((size_t)N * DIM * 2);
    unsigned short* h1  = (unsigned short*)alloc((size_t)N * DIM * 2);
    unsigned short* ngh = (unsigned short*)alloc((size_t)N * DIM * 2);

    detect_kernel<<<1, 64, 0, stream>>>((const unsigned int*)emb, flag);

    hipMemsetAsync(cnt, 0, (size_t)N * 4, stream);
    hist_kernel<<<(E + 255) / 256, 256, 0, stream>>>(edge_dst, cnt, E);
    scan_kernel<<<1, 1024, 0, stream>>>(cnt, row_ptr, N);
    scatter_kernel<<<(E + 255) / 256, 256, 0, stream>>>(edge_src, edge_dst, edge_w,
                                                        cnt, s_src, s_w, flag, E);

    const int WN = DIM * DIM;
    convert_kernel<<<(WN + 255) / 256, 256, 0, stream>>>(Ws1, Ws1c, WN, flag);
    convert_kernel<<<(WN + 255) / 256, 256, 0, stream>>>(Wn1, Wn1c, WN, flag);
    convert_kernel<<<(WN + 255) / 256, 256, 0, stream>>>(Ws2, Ws2c, WN, flag);
    convert_kernel<<<(WN + 255) / 256, 256, 0, stream>>>(Wn2, Wn2c, WN, flag);
    convert_kernel<<<1, 256, 0, stream>>>(b1, b1c, DIM, flag);
    convert_kernel<<<1, 256, 0, stream>>>(b2, b2c, DIM, flag);

    gather_h0<<<(N * 64 + 255) / 256, 256, 0, stream>>>(node_ids, emb,
                                                        (unsigned int*)h0, flag, N * 64);

    // Layer 1
    agg_kernel<<<(N + 3) / 4, 256, 0, stream>>>((const unsigned int*)h0, row_ptr,
                                                s_src, s_w, (unsigned int*)ngh, N, E);
    gemm_layer<<<(N + 63) / 64, 256, 0, stream>>>(h0, ngh, Ws1c, Wn1c, b1c,
                                                  h1, N, 1, 0, flag);

    // Layer 2
    agg_kernel<<<(N + 3) / 4, 256, 0, stream>>>((const unsigned int*)h1, row_ptr,
                                                s_src, s_w, (unsigned int*)ngh, N, E);
    gemm_layer<<<(N + 63) / 64, 256, 0, stream>>>(h1, ngh, Ws2c, Wn2c, b2c,
                                                  d_out, N, 0, 1, flag);
}

// Round 3
// 390.703 us; speedup vs baseline: 1.2874x; 1.2874x over previous
//
#include <hip/hip_runtime.h>
#include <stdint.h>

// N=50000 nodes, E=600000 edges, D=128.
#define DIM 128
#define SCAN_BLOCKS 256

typedef __attribute__((ext_vector_type(8))) short bf16x8;
typedef __attribute__((ext_vector_type(4))) float floatx4;

__device__ __forceinline__ float bf2f(unsigned short u) {
    union { unsigned int i; float f; } v; v.i = ((unsigned int)u) << 16; return v.f;
}
__device__ __forceinline__ unsigned short f2bf(float f) {
    union { float f; unsigned int i; } v; v.f = f;
    unsigned int r = (v.i + 0x7FFFu + ((v.i >> 16) & 1u)) >> 16;
    return (unsigned short)r;
}

// ---- dtype detection: 1 = fp32 inputs, 0 = bf16 inputs -----------------
__global__ void detect_kernel(const unsigned int* __restrict__ w32, int* __restrict__ flag) {
    int t = threadIdx.x;  // 64 threads
    unsigned int v = w32[t];
    float f = bf2f((unsigned short)(v & 0xffffu));
    int bad = !(fabsf(f) < 1e4f);   // catches NaN too
    unsigned long long m = __ballot(bad);
    if (t == 0) *flag = (__popcll(m) > 16) ? 1 : 0;
}

// ---- fused weight/bias canonicalization to one bf16 arena --------------
__global__ void convert_all(const void* __restrict__ s0, const void* __restrict__ s1,
                            const void* __restrict__ s2, const void* __restrict__ s3,
                            const void* __restrict__ s4, const void* __restrict__ s5,
                            unsigned short* __restrict__ dst, const int* __restrict__ flag) {
    const int W = DIM * DIM;
    int i = blockIdx.x * 256 + threadIdx.x;
    const void* src; int off;
    if      (i < W)             { src = s0; off = i; }
    else if (i < 2 * W)         { src = s1; off = i - W; }
    else if (i < 3 * W)         { src = s2; off = i - 2 * W; }
    else if (i < 4 * W)         { src = s3; off = i - 3 * W; }
    else if (i < 4 * W + DIM)   { src = s4; off = i - 4 * W; }
    else if (i < 4 * W + 2*DIM) { src = s5; off = i - 4 * W - DIM; }
    else return;
    dst[i] = (*flag) ? f2bf(((const float*)src)[off])
                     : ((const unsigned short*)src)[off];
}

// ---- CSR build ---------------------------------------------------------

__global__ void hist_kernel(const int* __restrict__ dst, int* __restrict__ cnt, int E) {
    int e = blockIdx.x * 256 + threadIdx.x;
    if (e < E) atomicAdd(&cnt[dst[e]], 1);
}

// Phase 1: per-block chunk sums.
__global__ __launch_bounds__(256) void scan_partial(const int* __restrict__ cnt,
                                                    int* __restrict__ partials, int N) {
    int b = blockIdx.x;
    int chunk = (N + gridDim.x - 1) / gridDim.x;
    int beg = b * chunk;
    int end = min(beg + chunk, N);
    int t = threadIdx.x;
    int s = 0;
    for (int i = beg + t; i < end; i += 256) s += cnt[i];
    for (int off = 32; off > 0; off >>= 1) s += __shfl_xor(s, off);
    __shared__ int ws[4];
    if ((t & 63) == 0) ws[t >> 6] = s;
    __syncthreads();
    if (t == 0) partials[b] = ws[0] + ws[1] + ws[2] + ws[3];
}

// Phase 2: exclusive scan of the 256 partials (single block).
__global__ __launch_bounds__(256) void scan_mid(int* __restrict__ partials, int B) {
    __shared__ int tmp[256];
    int t = threadIdx.x;
    int v = (t < B) ? partials[t] : 0;
    tmp[t] = v;
    __syncthreads();
    for (int off = 1; off < 256; off <<= 1) {
        int x = (t >= off) ? tmp[t - off] : 0;
        __syncthreads();
        tmp[t] += x;
        __syncthreads();
    }
    if (t < B) partials[t] = tmp[t] - v;   // exclusive
}

// Phase 3: per-block local exclusive scan + offset -> row_ptr & cursor.
__global__ __launch_bounds__(256) void scan_final(int* __restrict__ cnt,
                                                  int* __restrict__ row_ptr,
                                                  const int* __restrict__ block_off, int N) {
    __shared__ int tile[256];
    __shared__ int s_run;
    int b = blockIdx.x;
    int chunk = (N + gridDim.x - 1) / gridDim.x;
    int beg = b * chunk;
    int end = min(beg + chunk, N);
    int t = threadIdx.x;
    if (t == 0) s_run = block_off[b];
    __syncthreads();
    for (int base = beg; base < end; base += 256) {
        int i = base + t;
        int v = (i < end) ? cnt[i] : 0;
        tile[t] = v;
        __syncthreads();
        for (int off = 1; off < 256; off <<= 1) {
            int x = (t >= off) ? tile[t - off] : 0;
            __syncthreads();
            tile[t] += x;
            __syncthreads();
        }
        int run = s_run;
        if (i < end) {
            int start = run + tile[t] - v;
            row_ptr[i] = start;
            cnt[i] = start;                 // cursor = row start
            if (i == N - 1) row_ptr[N] = start + v;
        }
        __syncthreads();
        if (t == 255) s_run = run + tile[255];
        __syncthreads();
    }
}

__global__ void scatter_kernel(const int* __restrict__ src, const int* __restrict__ dst,
                               const void* __restrict__ w_any,
                               int* __restrict__ cursor,
                               int* __restrict__ s_src, float* __restrict__ s_w,
                               const int* __restrict__ flag, int E) {
    int e = blockIdx.x * 256 + threadIdx.x;
    if (e >= E) return;
    float wv = (*flag) ? ((const float*)w_any)[e]
                       : bf2f(((const unsigned short*)w_any)[e]);
    int d = dst[e];
    int pos = atomicAdd(&cursor[d], 1);
    s_src[pos] = src[e];
    s_w[pos] = wv;
}

// ---- h0 = emb[node_ids], canonicalized to bf16 -------------------------

__global__ void gather_h0(const int* __restrict__ ids, const void* __restrict__ emb,
                          unsigned int* __restrict__ h032,
                          const int* __restrict__ flag, int total) {
    int t = blockIdx.x * 256 + threadIdx.x;
    if (t >= total) return;
    int n = t >> 6;           // 64 uints (=128 bf16) per row
    int f = t & 63;
    int id = ids[n];
    unsigned int o;
    if (*flag) {
        const float* e = (const float*)emb + (size_t)id * DIM + f * 2;
        o = ((unsigned int)f2bf(e[1]) << 16) | (unsigned int)f2bf(e[0]);
    } else {
        o = ((const unsigned int*)emb)[(size_t)id * 64 + f];
    }
    h032[t] = o;
}

// ---- neighbor mean: one wave per node ----------------------------------

__global__ __launch_bounds__(256) void agg_kernel(const unsigned int* __restrict__ h32,
                                                  const int* __restrict__ row_ptr,
                                                  const int* __restrict__ s_src,
                                                  const float* __restrict__ s_w,
                                                  unsigned int* __restrict__ out32,
                                                  int N, int E) {
    int node = blockIdx.x * 4 + (threadIdx.x >> 6);
    int lane = threadIdx.x & 63;
    if (node >= N) return;
    int beg = max(row_ptr[node], 0);
    int end = min(row_ptr[node + 1], E);
    float a0 = 0.f, a1 = 0.f;
    for (int e = beg; e < end; ++e) {
        int s = s_src[e];
        if ((unsigned)s >= (unsigned)N) continue;   // safety: finite-wrong, not NaN
        float w = s_w[e];
        unsigned int v = h32[(size_t)s * 64 + lane];
        a0 += w * bf2f((unsigned short)(v & 0xffffu));
        a1 += w * bf2f((unsigned short)(v >> 16));
    }
    float inv = (end > beg) ? 1.0f / (float)(end - beg) : 0.f;
    a0 *= inv; a1 *= inv;
    unsigned int o = ((unsigned int)f2bf(a1) << 16) | (unsigned int)f2bf(a0);
    out32[(size_t)node * 64 + lane] = o;
}

// ---- fused SAGE linear: out = h @ Wself^T + b + neigh @ Wneigh^T (+relu)
// MFMA 16x16x32 bf16. Block = 4 waves; wave computes 16 rows x 128 cols.
// A frag: lane holds A[m=lane&15][k=quad*8+j]; B frag: W[n=lane&15][k=quad*8+j]
// C/D: D[row=quad*4+r][col=lane&15]

__global__ __launch_bounds__(256) void gemm_layer(const unsigned short* __restrict__ A0,
                                                  const unsigned short* __restrict__ A1,
                                                  const unsigned short* __restrict__ W0,
                                                  const unsigned short* __restrict__ W1,
                                                  const unsigned short* __restrict__ bias,
                                                  void* __restrict__ out,
                                                  int n_rows, int relu, int is_final,
                                                  const int* __restrict__ flag) {
    int wave = threadIdx.x >> 6;
    int lane = threadIdx.x & 63;
    int quad = lane >> 4;
    int l16  = lane & 15;
    int m_base = blockIdx.x * 64 + wave * 16;
    int fp32_out = is_final ? *flag : 0;

    floatx4 acc[8];
#pragma unroll
    for (int c = 0; c < 8; ++c) acc[c] = (floatx4){0.f, 0.f, 0.f, 0.f};

    int arow = m_base + l16;
    if (arow >= n_rows) arow = n_rows - 1;   // clamp; stores are guarded
    const unsigned short* Ar0 = A0 + (size_t)arow * DIM;
    const unsigned short* Ar1 = A1 + (size_t)arow * DIM;

#pragma unroll
    for (int ks = 0; ks < 4; ++ks) {
        int k0 = ks * 32 + quad * 8;
        bf16x8 a = *(const bf16x8*)(Ar0 + k0);
#pragma unroll
        for (int c = 0; c < 8; ++c) {
            bf16x8 b = *(const bf16x8*)(W0 + (size_t)(c * 16 + l16) * DIM + k0);
            acc[c] = __builtin_amdgcn_mfma_f32_16x16x32_bf16(a, b, acc[c], 0, 0, 0);
        }
    }
#pragma unroll
    for (int ks = 0; ks < 4; ++ks) {
        int k0 = ks * 32 + quad * 8;
        bf16x8 a = *(const bf16x8*)(Ar1 + k0);
#pragma unroll
        for (int c = 0; c < 8; ++c) {
            bf16x8 b = *(const bf16x8*)(W1 + (size_t)(c * 16 + l16) * DIM + k0);
            acc[c] = __builtin_amdgcn_mfma_f32_16x16x32_bf16(a, b, acc[c], 0, 0, 0);
        }
    }

#pragma unroll
    for (int c = 0; c < 8; ++c) {
        int col = c * 16 + l16;
        float bv = bf2f(bias[col]);
#pragma unroll
        for (int r = 0; r < 4; ++r) {
            int row = m_base + quad * 4 + r;
            if (row < n_rows) {
                float v = acc[c][r] + bv;
                if (relu) v = fmaxf(v, 0.f);
                size_t idx = (size_t)row * DIM + col;
                if (fp32_out) ((float*)out)[idx] = v;
                else          ((unsigned short*)out)[idx] = f2bf(v);
            }
        }
    }
}

// ---- launch ------------------------------------------------------------

extern "C" void kernel_launch(void* const* d_in, const int* in_sizes, int n_in,
                              void* d_out, int out_size, void* d_ws, size_t ws_size,
                              hipStream_t stream) {
    const int* node_ids = (const int*)d_in[0];
    const int* edge_src = (const int*)d_in[1];
    const int* edge_dst = (const int*)d_in[2];
    const void* edge_w  = d_in[3];
    const void* emb     = d_in[4];
    const void* Ws1     = d_in[5];
    const void* Wn1     = d_in[6];
    const void* b1      = d_in[7];
    const void* Ws2     = d_in[8];
    const void* Wn2     = d_in[9];
    const void* b2      = d_in[10];

    const int N = in_sizes[0];
    const int E = in_sizes[1];

    char* w = (char*)d_ws;
    auto alloc = [&](size_t bytes) {
        char* p = w;
        w += (bytes + 255) & ~(size_t)255;
        return p;
    };
    int* flag           = (int*)alloc(4);
    int* partials       = (int*)alloc((size_t)SCAN_BLOCKS * 4);
    int* row_ptr        = (int*)alloc((size_t)(N + 1) * 4);
    int* cnt            = (int*)alloc((size_t)N * 4);
    // one contiguous bf16 arena: Ws1|Wn1|Ws2|Wn2|b1|b2
    const int W = DIM * DIM;
    unsigned short* wcat = (unsigned short*)alloc((size_t)(4 * W + 2 * DIM) * 2);
    unsigned short* Ws1c = wcat;
    unsigned short* Wn1c = wcat + W;
    unsigned short* Ws2c = wcat + 2 * W;
    unsigned short* Wn2c = wcat + 3 * W;
    unsigned short* b1c  = wcat + 4 * W;
    unsigned short* b2c  = wcat + 4 * W + DIM;
    int* s_src          = (int*)alloc((size_t)E * 4);
    float* s_w          = (float*)alloc((size_t)E * 4);
    unsigned short* h0  = (unsigned short*)alloc((size_t)N * DIM * 2);
    unsigned short* h1  = (unsigned short*)alloc((size_t)N * DIM * 2);
    unsigned short* ngh = (unsigned short*)alloc((size_t)N * DIM * 2);

    detect_kernel<<<1, 64, 0, stream>>>((const unsigned int*)emb, flag);

    hipMemsetAsync(cnt, 0, (size_t)N * 4, stream);
    hist_kernel<<<(E + 255) / 256, 256, 0, stream>>>(edge_dst, cnt, E);
    scan_partial<<<SCAN_BLOCKS, 256, 0, stream>>>(cnt, partials, N);
    scan_mid<<<1, 256, 0, stream>>>(partials, SCAN_BLOCKS);
    scan_final<<<SCAN_BLOCKS, 256, 0, stream>>>(cnt, row_ptr, partials, N);
    scatter_kernel<<<(E + 255) / 256, 256, 0, stream>>>(edge_src, edge_dst, edge_w,
                                                        cnt, s_src, s_w, flag, E);

    const int CN = 4 * W + 2 * DIM;
    convert_all<<<(CN + 255) / 256, 256, 0, stream>>>(Ws1, Wn1, Ws2, Wn2, b1, b2,
                                                      wcat, flag);

    gather_h0<<<(N * 64 + 255) / 256, 256, 0, stream>>>(node_ids, emb,
                                                        (unsigned int*)h0, flag, N * 64);

    // Layer 1
    agg_kernel<<<(N + 3) / 4, 256, 0, stream>>>((const unsigned int*)h0, row_ptr,
                                                s_src, s_w, (unsigned int*)ngh, N, E);
    gemm_layer<<<(N + 63) / 64, 256, 0, stream>>>(h0, ngh, Ws1c, Wn1c, b1c,
                                                  h1, N, 1, 0, flag);

    // Layer 2
    agg_kernel<<<(N + 3) / 4, 256, 0, stream>>>((const unsigned int*)h1, row_ptr,
                                                s_src, s_w, (unsigned int*)ngh, N, E);
    gemm_layer<<<(N + 63) / 64, 256, 0, stream>>>(h1, ngh, Ws2c, Wn2c, b2c,
                                                  d_out, N, 0, 1, flag);
}

// Round 4
// 324.296 us; speedup vs baseline: 1.5510x; 1.2048x over previous
//
#include <hip/hip_runtime.h>
#include <stdint.h>

// N=50000 nodes, E=600000 edges, D=128.
#define DIM 128
#define SCAN_BLOCKS 256

typedef __attribute__((ext_vector_type(8))) short bf16x8;
typedef __attribute__((ext_vector_type(4))) float floatx4;

__device__ __forceinline__ float bf2f(unsigned short u) {
    union { unsigned int i; float f; } v; v.i = ((unsigned int)u) << 16; return v.f;
}
__device__ __forceinline__ unsigned short f2bf(float f) {
    union { float f; unsigned int i; } v; v.f = f;
    unsigned int r = (v.i + 0x7FFFu + ((v.i >> 16) & 1u)) >> 16;
    return (unsigned short)r;
}

// ---- dtype detection: 1 = fp32 inputs, 0 = bf16 inputs -----------------
__global__ void detect_kernel(const unsigned int* __restrict__ w32, int* __restrict__ flag) {
    int t = threadIdx.x;  // 64 threads
    unsigned int v = w32[t];
    float f = bf2f((unsigned short)(v & 0xffffu));
    int bad = !(fabsf(f) < 1e4f);   // catches NaN too
    unsigned long long m = __ballot(bad);
    if (t == 0) *flag = (__popcll(m) > 16) ? 1 : 0;
}

// ---- fused weight/bias canonicalization to one bf16 arena --------------
__global__ void convert_all(const void* __restrict__ s0, const void* __restrict__ s1,
                            const void* __restrict__ s2, const void* __restrict__ s3,
                            const void* __restrict__ s4, const void* __restrict__ s5,
                            unsigned short* __restrict__ dst, const int* __restrict__ flag) {
    const int W = DIM * DIM;
    int i = blockIdx.x * 256 + threadIdx.x;
    const void* src; int off;
    if      (i < W)             { src = s0; off = i; }
    else if (i < 2 * W)         { src = s1; off = i - W; }
    else if (i < 3 * W)         { src = s2; off = i - 2 * W; }
    else if (i < 4 * W)         { src = s3; off = i - 3 * W; }
    else if (i < 4 * W + DIM)   { src = s4; off = i - 4 * W; }
    else if (i < 4 * W + 2*DIM) { src = s5; off = i - 4 * W - DIM; }
    else return;
    dst[i] = (*flag) ? f2bf(((const float*)src)[off])
                     : ((const unsigned short*)src)[off];
}

// ---- CSR build ---------------------------------------------------------

__global__ void hist_kernel(const int* __restrict__ dst, int* __restrict__ cnt, int E) {
    int e = blockIdx.x * 256 + threadIdx.x;
    if (e < E) atomicAdd(&cnt[dst[e]], 1);
}

// Phase 1: per-block chunk sums.
__global__ __launch_bounds__(256) void scan_partial(const int* __restrict__ cnt,
                                                    int* __restrict__ partials, int N) {
    int b = blockIdx.x;
    int chunk = (N + gridDim.x - 1) / gridDim.x;
    int beg = b * chunk;
    int end = min(beg + chunk, N);
    int t = threadIdx.x;
    int s = 0;
    for (int i = beg + t; i < end; i += 256) s += cnt[i];
    for (int off = 32; off > 0; off >>= 1) s += __shfl_xor(s, off);
    __shared__ int ws[4];
    if ((t & 63) == 0) ws[t >> 6] = s;
    __syncthreads();
    if (t == 0) partials[b] = ws[0] + ws[1] + ws[2] + ws[3];
}

// Phase 2: exclusive scan of the 256 partials (single block).
__global__ __launch_bounds__(256) void scan_mid(int* __restrict__ partials, int B) {
    __shared__ int tmp[256];
    int t = threadIdx.x;
    int v = (t < B) ? partials[t] : 0;
    tmp[t] = v;
    __syncthreads();
    for (int off = 1; off < 256; off <<= 1) {
        int x = (t >= off) ? tmp[t - off] : 0;
        __syncthreads();
        tmp[t] += x;
        __syncthreads();
    }
    if (t < B) partials[t] = tmp[t] - v;   // exclusive
}

// Phase 3: per-block local exclusive scan + offset -> row_ptr & cursor.
__global__ __launch_bounds__(256) void scan_final(int* __restrict__ cnt,
                                                  int* __restrict__ row_ptr,
                                                  const int* __restrict__ block_off, int N) {
    __shared__ int tile[256];
    __shared__ int s_run;
    int b = blockIdx.x;
    int chunk = (N + gridDim.x - 1) / gridDim.x;
    int beg = b * chunk;
    int end = min(beg + chunk, N);
    int t = threadIdx.x;
    if (t == 0) s_run = block_off[b];
    __syncthreads();
    for (int base = beg; base < end; base += 256) {
        int i = base + t;
        int v = (i < end) ? cnt[i] : 0;
        tile[t] = v;
        __syncthreads();
        for (int off = 1; off < 256; off <<= 1) {
            int x = (t >= off) ? tile[t - off] : 0;
            __syncthreads();
            tile[t] += x;
            __syncthreads();
        }
        int run = s_run;
        if (i < end) {
            int start = run + tile[t] - v;
            row_ptr[i] = start;
            cnt[i] = start;                 // cursor = row start
            if (i == N - 1) row_ptr[N] = start + v;
        }
        __syncthreads();
        if (t == 255) s_run = run + tile[255];
        __syncthreads();
    }
}

__global__ void scatter_kernel(const int* __restrict__ src, const int* __restrict__ dst,
                               const void* __restrict__ w_any,
                               int* __restrict__ cursor,
                               int* __restrict__ s_src, float* __restrict__ s_w,
                               const int* __restrict__ flag, int E) {
    int e = blockIdx.x * 256 + threadIdx.x;
    if (e >= E) return;
    float wv = (*flag) ? ((const float*)w_any)[e]
                       : bf2f(((const unsigned short*)w_any)[e]);
    int d = dst[e];
    int pos = atomicAdd(&cursor[d], 1);
    s_src[pos] = src[e];
    s_w[pos] = wv;
}

// ---- h0 = emb[node_ids], canonicalized to bf16 -------------------------

__global__ void gather_h0(const int* __restrict__ ids, const void* __restrict__ emb,
                          unsigned int* __restrict__ h032,
                          const int* __restrict__ flag, int total) {
    int t = blockIdx.x * 256 + threadIdx.x;
    if (t >= total) return;
    int n = t >> 6;           // 64 uints (=128 bf16) per row
    int f = t & 63;
    int id = ids[n];
    unsigned int o;
    if (*flag) {
        const float* e = (const float*)emb + (size_t)id * DIM + f * 2;
        o = ((unsigned int)f2bf(e[1]) << 16) | (unsigned int)f2bf(e[0]);
    } else {
        o = ((const unsigned int*)emb)[(size_t)id * 64 + f];
    }
    h032[t] = o;
}

// ---- neighbor mean: one wave per node, edge loop unrolled x4 for MLP ----

__device__ __forceinline__ void agg_edge(const unsigned int* __restrict__ h32,
                                         int s, float w, int lane, int N,
                                         float& a0, float& a1) {
    int ok = ((unsigned)s < (unsigned)N);
    s = ok ? s : 0;
    w = ok ? w : 0.f;
    unsigned int v = h32[(size_t)s * 64 + lane];
    a0 += w * bf2f((unsigned short)(v & 0xffffu));
    a1 += w * bf2f((unsigned short)(v >> 16));
}

__global__ __launch_bounds__(256) void agg_kernel(const unsigned int* __restrict__ h32,
                                                  const int* __restrict__ row_ptr,
                                                  const int* __restrict__ s_src,
                                                  const float* __restrict__ s_w,
                                                  unsigned int* __restrict__ out32,
                                                  int N, int E) {
    int node = blockIdx.x * 4 + (threadIdx.x >> 6);
    int lane = threadIdx.x & 63;
    if (node >= N) return;
    int beg = max(row_ptr[node], 0);
    int end = min(row_ptr[node + 1], E);
    float a0 = 0.f, a1 = 0.f;
    int e = beg;
    for (; e + 4 <= end; e += 4) {
        int s0 = s_src[e],     s1 = s_src[e + 1];
        int s2 = s_src[e + 2], s3 = s_src[e + 3];
        float w0 = s_w[e],     w1 = s_w[e + 1];
        float w2 = s_w[e + 2], w3 = s_w[e + 3];
        int k0 = ((unsigned)s0 < (unsigned)N) ? s0 : 0;  if (k0 != s0) w0 = 0.f;
        int k1 = ((unsigned)s1 < (unsigned)N) ? s1 : 0;  if (k1 != s1) w1 = 0.f;
        int k2 = ((unsigned)s2 < (unsigned)N) ? s2 : 0;  if (k2 != s2) w2 = 0.f;
        int k3 = ((unsigned)s3 < (unsigned)N) ? s3 : 0;  if (k3 != s3) w3 = 0.f;
        unsigned int v0 = h32[(size_t)k0 * 64 + lane];
        unsigned int v1 = h32[(size_t)k1 * 64 + lane];
        unsigned int v2 = h32[(size_t)k2 * 64 + lane];
        unsigned int v3 = h32[(size_t)k3 * 64 + lane];
        a0 += w0 * bf2f((unsigned short)(v0 & 0xffffu));
        a1 += w0 * bf2f((unsigned short)(v0 >> 16));
        a0 += w1 * bf2f((unsigned short)(v1 & 0xffffu));
        a1 += w1 * bf2f((unsigned short)(v1 >> 16));
        a0 += w2 * bf2f((unsigned short)(v2 & 0xffffu));
        a1 += w2 * bf2f((unsigned short)(v2 >> 16));
        a0 += w3 * bf2f((unsigned short)(v3 & 0xffffu));
        a1 += w3 * bf2f((unsigned short)(v3 >> 16));
    }
    for (; e < end; ++e) {
        agg_edge(h32, s_src[e], s_w[e], lane, N, a0, a1);
    }
    float inv = (end > beg) ? 1.0f / (float)(end - beg) : 0.f;
    a0 *= inv; a1 *= inv;
    unsigned int o = ((unsigned int)f2bf(a1) << 16) | (unsigned int)f2bf(a0);
    out32[(size_t)node * 64 + lane] = o;
}

// ---- fused SAGE linear: out = h @ Wself^T + b + neigh @ Wneigh^T (+relu)
// MFMA 16x16x32 bf16. Block = 4 waves; wave computes 16 rows x 128 cols.
// A frag: lane holds A[m=lane&15][k=quad*8+j]; B frag: W[n=lane&15][k=quad*8+j]
// C/D: D[row=quad*4+r][col=lane&15]

__global__ __launch_bounds__(256) void gemm_layer(const unsigned short* __restrict__ A0,
                                                  const unsigned short* __restrict__ A1,
                                                  const unsigned short* __restrict__ W0,
                                                  const unsigned short* __restrict__ W1,
                                                  const unsigned short* __restrict__ bias,
                                                  void* __restrict__ out,
                                                  int n_rows, int relu, int is_final,
                                                  const int* __restrict__ flag) {
    int wave = threadIdx.x >> 6;
    int lane = threadIdx.x & 63;
    int quad = lane >> 4;
    int l16  = lane & 15;
    int m_base = blockIdx.x * 64 + wave * 16;
    int fp32_out = is_final ? *flag : 0;

    floatx4 acc[8];
#pragma unroll
    for (int c = 0; c < 8; ++c) acc[c] = (floatx4){0.f, 0.f, 0.f, 0.f};

    int arow = m_base + l16;
    if (arow >= n_rows) arow = n_rows - 1;   // clamp; stores are guarded
    const unsigned short* Ar0 = A0 + (size_t)arow * DIM;
    const unsigned short* Ar1 = A1 + (size_t)arow * DIM;

#pragma unroll
    for (int ks = 0; ks < 4; ++ks) {
        int k0 = ks * 32 + quad * 8;
        bf16x8 a = *(const bf16x8*)(Ar0 + k0);
#pragma unroll
        for (int c = 0; c < 8; ++c) {
            bf16x8 b = *(const bf16x8*)(W0 + (size_t)(c * 16 + l16) * DIM + k0);
            acc[c] = __builtin_amdgcn_mfma_f32_16x16x32_bf16(a, b, acc[c], 0, 0, 0);
        }
    }
#pragma unroll
    for (int ks = 0; ks < 4; ++ks) {
        int k0 = ks * 32 + quad * 8;
        bf16x8 a = *(const bf16x8*)(Ar1 + k0);
#pragma unroll
        for (int c = 0; c < 8; ++c) {
            bf16x8 b = *(const bf16x8*)(W1 + (size_t)(c * 16 + l16) * DIM + k0);
            acc[c] = __builtin_amdgcn_mfma_f32_16x16x32_bf16(a, b, acc[c], 0, 0, 0);
        }
    }

#pragma unroll
    for (int c = 0; c < 8; ++c) {
        int col = c * 16 + l16;
        float bv = bf2f(bias[col]);
#pragma unroll
        for (int r = 0; r < 4; ++r) {
            int row = m_base + quad * 4 + r;
            if (row < n_rows) {
                float v = acc[c][r] + bv;
                if (relu) v = fmaxf(v, 0.f);
                size_t idx = (size_t)row * DIM + col;
                if (fp32_out) ((float*)out)[idx] = v;
                else          ((unsigned short*)out)[idx] = f2bf(v);
            }
        }
    }
}

// ---- launch ------------------------------------------------------------

extern "C" void kernel_launch(void* const* d_in, const int* in_sizes, int n_in,
                              void* d_out, int out_size, void* d_ws, size_t ws_size,
                              hipStream_t stream) {
    const int* node_ids = (const int*)d_in[0];
    const int* edge_src = (const int*)d_in[1];
    const int* edge_dst = (const int*)d_in[2];
    const void* edge_w  = d_in[3];
    const void* emb     = d_in[4];
    const void* Ws1     = d_in[5];
    const void* Wn1     = d_in[6];
    const void* b1      = d_in[7];
    const void* Ws2     = d_in[8];
    const void* Wn2     = d_in[9];
    const void* b2      = d_in[10];

    const int N = in_sizes[0];
    const int E = in_sizes[1];

    char* w = (char*)d_ws;
    auto alloc = [&](size_t bytes) {
        char* p = w;
        w += (bytes + 255) & ~(size_t)255;
        return p;
    };
    int* flag           = (int*)alloc(4);
    int* partials       = (int*)alloc((size_t)SCAN_BLOCKS * 4);
    int* row_ptr        = (int*)alloc((size_t)(N + 1) * 4);
    int* cnt            = (int*)alloc((size_t)N * 4);
    const int W = DIM * DIM;
    unsigned short* wcat = (unsigned short*)alloc((size_t)(4 * W + 2 * DIM) * 2);
    unsigned short* Ws1c = wcat;
    unsigned short* Wn1c = wcat + W;
    unsigned short* Ws2c = wcat + 2 * W;
    unsigned short* Wn2c = wcat + 3 * W;
    unsigned short* b1c  = wcat + 4 * W;
    unsigned short* b2c  = wcat + 4 * W + DIM;
    int* s_src          = (int*)alloc((size_t)E * 4);
    float* s_w          = (float*)alloc((size_t)E * 4);
    unsigned short* h0  = (unsigned short*)alloc((size_t)N * DIM * 2);
    unsigned short* h1  = (unsigned short*)alloc((size_t)N * DIM * 2);
    unsigned short* ngh = (unsigned short*)alloc((size_t)N * DIM * 2);

    detect_kernel<<<1, 64, 0, stream>>>((const unsigned int*)emb, flag);

    hipMemsetAsync(cnt, 0, (size_t)N * 4, stream);
    hist_kernel<<<(E + 255) / 256, 256, 0, stream>>>(edge_dst, cnt, E);
    scan_partial<<<SCAN_BLOCKS, 256, 0, stream>>>(cnt, partials, N);
    scan_mid<<<1, 256, 0, stream>>>(partials, SCAN_BLOCKS);
    scan_final<<<SCAN_BLOCKS, 256, 0, stream>>>(cnt, row_ptr, partials, N);
    scatter_kernel<<<(E + 255) / 256, 256, 0, stream>>>(edge_src, edge_dst, edge_w,
                                                        cnt, s_src, s_w, flag, E);

    const int CN = 4 * W + 2 * DIM;
    convert_all<<<(CN + 255) / 256, 256, 0, stream>>>(Ws1, Wn1, Ws2, Wn2, b1, b2,
                                                      wcat, flag);

    gather_h0<<<(N * 64 + 255) / 256, 256, 0, stream>>>(node_ids, emb,
                                                        (unsigned int*)h0, flag, N * 64);

    // Layer 1
    agg_kernel<<<(N + 3) / 4, 256, 0, stream>>>((const unsigned int*)h0, row_ptr,
                                                s_src, s_w, (unsigned int*)ngh, N, E);
    gemm_layer<<<(N + 63) / 64, 256, 0, stream>>>(h0, ngh, Ws1c, Wn1c, b1c,
                                                  h1, N, 1, 0, flag);

    // Layer 2
    agg_kernel<<<(N + 3) / 4, 256, 0, stream>>>((const unsigned int*)h1, row_ptr,
                                                s_src, s_w, (unsigned int*)ngh, N, E);
    gemm_layer<<<(N + 63) / 64, 256, 0, stream>>>(h1, ngh, Ws2c, Wn2c, b2c,
                                                  d_out, N, 0, 1, flag);
}

// Round 5
// 308.438 us; speedup vs baseline: 1.6308x; 1.0514x over previous
//
#include <hip/hip_runtime.h>
#include <stdint.h>

// N=50000 nodes, E=600000 edges, D=128.  NOTE: edge records pack src into
// 16 bits -> requires N <= 65536 (true for this problem's fixed N=50000).
#define DIM 128
#define SCAN_BLOCKS 256

typedef __attribute__((ext_vector_type(8))) short bf16x8;
typedef __attribute__((ext_vector_type(4))) float floatx4;

__device__ __forceinline__ float bf2f(unsigned short u) {
    union { unsigned int i; float f; } v; v.i = ((unsigned int)u) << 16; return v.f;
}
__device__ __forceinline__ unsigned short f2bf(float f) {
    union { float f; unsigned int i; } v; v.f = f;
    unsigned int r = (v.i + 0x7FFFu + ((v.i >> 16) & 1u)) >> 16;
    return (unsigned short)r;
}

// ---- dtype detection: 1 = fp32 inputs, 0 = bf16 inputs -----------------
__global__ void detect_kernel(const unsigned int* __restrict__ w32, int* __restrict__ flag) {
    int t = threadIdx.x;  // 64 threads
    unsigned int v = w32[t];
    float f = bf2f((unsigned short)(v & 0xffffu));
    int bad = !(fabsf(f) < 1e4f);   // catches NaN too
    unsigned long long m = __ballot(bad);
    if (t == 0) *flag = (__popcll(m) > 16) ? 1 : 0;
}

// ---- fused weight/bias canonicalization to one bf16 arena --------------
__global__ void convert_all(const void* __restrict__ s0, const void* __restrict__ s1,
                            const void* __restrict__ s2, const void* __restrict__ s3,
                            const void* __restrict__ s4, const void* __restrict__ s5,
                            unsigned short* __restrict__ dst, const int* __restrict__ flag) {
    const int W = DIM * DIM;
    int i = blockIdx.x * 256 + threadIdx.x;
    const void* src; int off;
    if      (i < W)             { src = s0; off = i; }
    else if (i < 2 * W)         { src = s1; off = i - W; }
    else if (i < 3 * W)         { src = s2; off = i - 2 * W; }
    else if (i < 4 * W)         { src = s3; off = i - 3 * W; }
    else if (i < 4 * W + DIM)   { src = s4; off = i - 4 * W; }
    else if (i < 4 * W + 2*DIM) { src = s5; off = i - 4 * W - DIM; }
    else return;
    dst[i] = (*flag) ? f2bf(((const float*)src)[off])
                     : ((const unsigned short*)src)[off];
}

// ---- CSR build ---------------------------------------------------------

__global__ void hist_kernel(const int* __restrict__ dst, int* __restrict__ cnt, int E) {
    int e = blockIdx.x * 256 + threadIdx.x;
    if (e < E) atomicAdd(&cnt[dst[e]], 1);
}

// Phase 1: per-block chunk sums.
__global__ __launch_bounds__(256) void scan_partial(const int* __restrict__ cnt,
                                                    int* __restrict__ partials, int N) {
    int b = blockIdx.x;
    int chunk = (N + gridDim.x - 1) / gridDim.x;
    int beg = b * chunk;
    int end = min(beg + chunk, N);
    int t = threadIdx.x;
    int s = 0;
    for (int i = beg + t; i < end; i += 256) s += cnt[i];
    for (int off = 32; off > 0; off >>= 1) s += __shfl_xor(s, off);
    __shared__ int ws[4];
    if ((t & 63) == 0) ws[t >> 6] = s;
    __syncthreads();
    if (t == 0) partials[b] = ws[0] + ws[1] + ws[2] + ws[3];
}

// Phase 2: exclusive scan of the 256 partials (single block).
__global__ __launch_bounds__(256) void scan_mid(int* __restrict__ partials, int B) {
    __shared__ int tmp[256];
    int t = threadIdx.x;
    int v = (t < B) ? partials[t] : 0;
    tmp[t] = v;
    __syncthreads();
    for (int off = 1; off < 256; off <<= 1) {
        int x = (t >= off) ? tmp[t - off] : 0;
        __syncthreads();
        tmp[t] += x;
        __syncthreads();
    }
    if (t < B) partials[t] = tmp[t] - v;   // exclusive
}

// Phase 3: per-block local exclusive scan + offset -> row_ptr & cursor.
__global__ __launch_bounds__(256) void scan_final(int* __restrict__ cnt,
                                                  int* __restrict__ row_ptr,
                                                  const int* __restrict__ block_off, int N) {
    __shared__ int tile[256];
    __shared__ int s_run;
    int b = blockIdx.x;
    int chunk = (N + gridDim.x - 1) / gridDim.x;
    int beg = b * chunk;
    int end = min(beg + chunk, N);
    int t = threadIdx.x;
    if (t == 0) s_run = block_off[b];
    __syncthreads();
    for (int base = beg; base < end; base += 256) {
        int i = base + t;
        int v = (i < end) ? cnt[i] : 0;
        tile[t] = v;
        __syncthreads();
        for (int off = 1; off < 256; off <<= 1) {
            int x = (t >= off) ? tile[t - off] : 0;
            __syncthreads();
            tile[t] += x;
            __syncthreads();
        }
        int run = s_run;
        if (i < end) {
            int start = run + tile[t] - v;
            row_ptr[i] = start;
            cnt[i] = start;                 // cursor = row start
            if (i == N - 1) row_ptr[N] = start + v;
        }
        __syncthreads();
        if (t == 255) s_run = run + tile[255];
        __syncthreads();
    }
}

// One packed 4B record per edge: src16 | (w_bf16 << 16). Single scattered
// store per edge halves randomly-dirtied HBM lines vs two 4B stores.
__global__ void scatter_kernel(const int* __restrict__ src, const int* __restrict__ dst,
                               const void* __restrict__ w_any,
                               int* __restrict__ cursor,
                               unsigned int* __restrict__ s_edge,
                               const int* __restrict__ flag, int E) {
    int e = blockIdx.x * 256 + threadIdx.x;
    if (e >= E) return;
    unsigned short wb = (*flag) ? f2bf(((const float*)w_any)[e])
                                : ((const unsigned short*)w_any)[e];
    int d = dst[e];
    unsigned int rec = ((unsigned int)src[e] & 0xffffu) | ((unsigned int)wb << 16);
    int pos = atomicAdd(&cursor[d], 1);
    s_edge[pos] = rec;
}

// ---- h0 = emb[node_ids], canonicalized to bf16 -------------------------

__global__ void gather_h0(const int* __restrict__ ids, const void* __restrict__ emb,
                          unsigned int* __restrict__ h032,
                          const int* __restrict__ flag, int total) {
    int t = blockIdx.x * 256 + threadIdx.x;
    if (t >= total) return;
    int n = t >> 6;           // 64 uints (=128 bf16) per row
    int f = t & 63;
    int id = ids[n];
    unsigned int o;
    if (*flag) {
        const float* e = (const float*)emb + (size_t)id * DIM + f * 2;
        o = ((unsigned int)f2bf(e[1]) << 16) | (unsigned int)f2bf(e[0]);
    } else {
        o = ((const unsigned int*)emb)[(size_t)id * 64 + f];
    }
    h032[t] = o;
}

// ---- neighbor mean: one wave per node, edge loop unrolled x4 for MLP ----

__global__ __launch_bounds__(256) void agg_kernel(const unsigned int* __restrict__ h32,
                                                  const int* __restrict__ row_ptr,
                                                  const unsigned int* __restrict__ s_edge,
                                                  unsigned int* __restrict__ out32,
                                                  int N, int E) {
    int node = blockIdx.x * 4 + (threadIdx.x >> 6);
    int lane = threadIdx.x & 63;
    if (node >= N) return;
    int beg = max(row_ptr[node], 0);
    int end = min(row_ptr[node + 1], E);
    float a0 = 0.f, a1 = 0.f;
    int e = beg;
    for (; e + 4 <= end; e += 4) {
        unsigned int r0 = s_edge[e],     r1 = s_edge[e + 1];
        unsigned int r2 = s_edge[e + 2], r3 = s_edge[e + 3];
        int k0 = min((int)(r0 & 0xffffu), N - 1);
        int k1 = min((int)(r1 & 0xffffu), N - 1);
        int k2 = min((int)(r2 & 0xffffu), N - 1);
        int k3 = min((int)(r3 & 0xffffu), N - 1);
        float w0 = bf2f((unsigned short)(r0 >> 16));
        float w1 = bf2f((unsigned short)(r1 >> 16));
        float w2 = bf2f((unsigned short)(r2 >> 16));
        float w3 = bf2f((unsigned short)(r3 >> 16));
        unsigned int v0 = h32[(size_t)k0 * 64 + lane];
        unsigned int v1 = h32[(size_t)k1 * 64 + lane];
        unsigned int v2 = h32[(size_t)k2 * 64 + lane];
        unsigned int v3 = h32[(size_t)k3 * 64 + lane];
        a0 += w0 * bf2f((unsigned short)(v0 & 0xffffu));
        a1 += w0 * bf2f((unsigned short)(v0 >> 16));
        a0 += w1 * bf2f((unsigned short)(v1 & 0xffffu));
        a1 += w1 * bf2f((unsigned short)(v1 >> 16));
        a0 += w2 * bf2f((unsigned short)(v2 & 0xffffu));
        a1 += w2 * bf2f((unsigned short)(v2 >> 16));
        a0 += w3 * bf2f((unsigned short)(v3 & 0xffffu));
        a1 += w3 * bf2f((unsigned short)(v3 >> 16));
    }
    for (; e < end; ++e) {
        unsigned int r = s_edge[e];
        int k = min((int)(r & 0xffffu), N - 1);
        float w = bf2f((unsigned short)(r >> 16));
        unsigned int v = h32[(size_t)k * 64 + lane];
        a0 += w * bf2f((unsigned short)(v & 0xffffu));
        a1 += w * bf2f((unsigned short)(v >> 16));
    }
    float inv = (end > beg) ? 1.0f / (float)(end - beg) : 0.f;
    a0 *= inv; a1 *= inv;
    unsigned int o = ((unsigned int)f2bf(a1) << 16) | (unsigned int)f2bf(a0);
    out32[(size_t)node * 64 + lane] = o;
}

// ---- fused SAGE linear: out = h @ Wself^T + b + neigh @ Wneigh^T (+relu)
// MFMA 16x16x32 bf16. Block = 4 waves; wave computes 16 rows x 128 cols.
// A frag: lane holds A[m=lane&15][k=quad*8+j]; B frag: W[n=lane&15][k=quad*8+j]
// C/D: D[row=quad*4+r][col=lane&15]

__global__ __launch_bounds__(256) void gemm_layer(const unsigned short* __restrict__ A0,
                                                  const unsigned short* __restrict__ A1,
                                                  const unsigned short* __restrict__ W0,
                                                  const unsigned short* __restrict__ W1,
                                                  const unsigned short* __restrict__ bias,
                                                  void* __restrict__ out,
                                                  int n_rows, int relu, int is_final,
                                                  const int* __restrict__ flag) {
    int wave = threadIdx.x >> 6;
    int lane = threadIdx.x & 63;
    int quad = lane >> 4;
    int l16  = lane & 15;
    int m_base = blockIdx.x * 64 + wave * 16;
    int fp32_out = is_final ? *flag : 0;

    floatx4 acc[8];
#pragma unroll
    for (int c = 0; c < 8; ++c) acc[c] = (floatx4){0.f, 0.f, 0.f, 0.f};

    int arow = m_base + l16;
    if (arow >= n_rows) arow = n_rows - 1;   // clamp; stores are guarded
    const unsigned short* Ar0 = A0 + (size_t)arow * DIM;
    const unsigned short* Ar1 = A1 + (size_t)arow * DIM;

#pragma unroll
    for (int ks = 0; ks < 4; ++ks) {
        int k0 = ks * 32 + quad * 8;
        bf16x8 a = *(const bf16x8*)(Ar0 + k0);
#pragma unroll
        for (int c = 0; c < 8; ++c) {
            bf16x8 b = *(const bf16x8*)(W0 + (size_t)(c * 16 + l16) * DIM + k0);
            acc[c] = __builtin_amdgcn_mfma_f32_16x16x32_bf16(a, b, acc[c], 0, 0, 0);
        }
    }
#pragma unroll
    for (int ks = 0; ks < 4; ++ks) {
        int k0 = ks * 32 + quad * 8;
        bf16x8 a = *(const bf16x8*)(Ar1 + k0);
#pragma unroll
        for (int c = 0; c < 8; ++c) {
            bf16x8 b = *(const bf16x8*)(W1 + (size_t)(c * 16 + l16) * DIM + k0);
            acc[c] = __builtin_amdgcn_mfma_f32_16x16x32_bf16(a, b, acc[c], 0, 0, 0);
        }
    }

#pragma unroll
    for (int c = 0; c < 8; ++c) {
        int col = c * 16 + l16;
        float bv = bf2f(bias[col]);
#pragma unroll
        for (int r = 0; r < 4; ++r) {
            int row = m_base + quad * 4 + r;
            if (row < n_rows) {
                float v = acc[c][r] + bv;
                if (relu) v = fmaxf(v, 0.f);
                size_t idx = (size_t)row * DIM + col;
                if (fp32_out) ((float*)out)[idx] = v;
                else          ((unsigned short*)out)[idx] = f2bf(v);
            }
        }
    }
}

// ---- launch ------------------------------------------------------------

extern "C" void kernel_launch(void* const* d_in, const int* in_sizes, int n_in,
                              void* d_out, int out_size, void* d_ws, size_t ws_size,
                              hipStream_t stream) {
    const int* node_ids = (const int*)d_in[0];
    const int* edge_src = (const int*)d_in[1];
    const int* edge_dst = (const int*)d_in[2];
    const void* edge_w  = d_in[3];
    const void* emb     = d_in[4];
    const void* Ws1     = d_in[5];
    const void* Wn1     = d_in[6];
    const void* b1      = d_in[7];
    const void* Ws2     = d_in[8];
    const void* Wn2     = d_in[9];
    const void* b2      = d_in[10];

    const int N = in_sizes[0];
    const int E = in_sizes[1];

    char* w = (char*)d_ws;
    auto alloc = [&](size_t bytes) {
        char* p = w;
        w += (bytes + 255) & ~(size_t)255;
        return p;
    };
    int* flag           = (int*)alloc(4);
    int* partials       = (int*)alloc((size_t)SCAN_BLOCKS * 4);
    int* row_ptr        = (int*)alloc((size_t)(N + 1) * 4);
    int* cnt            = (int*)alloc((size_t)N * 4);
    const int W = DIM * DIM;
    unsigned short* wcat = (unsigned short*)alloc((size_t)(4 * W + 2 * DIM) * 2);
    unsigned short* Ws1c = wcat;
    unsigned short* Wn1c = wcat + W;
    unsigned short* Ws2c = wcat + 2 * W;
    unsigned short* Wn2c = wcat + 3 * W;
    unsigned short* b1c  = wcat + 4 * W;
    unsigned short* b2c  = wcat + 4 * W + DIM;
    unsigned int* s_edge = (unsigned int*)alloc((size_t)E * 4);
    unsigned short* h0  = (unsigned short*)alloc((size_t)N * DIM * 2);
    unsigned short* h1  = (unsigned short*)alloc((size_t)N * DIM * 2);
    unsigned short* ngh = (unsigned short*)alloc((size_t)N * DIM * 2);

    detect_kernel<<<1, 64, 0, stream>>>((const unsigned int*)emb, flag);

    hipMemsetAsync(cnt, 0, (size_t)N * 4, stream);
    hist_kernel<<<(E + 255) / 256, 256, 0, stream>>>(edge_dst, cnt, E);
    scan_partial<<<SCAN_BLOCKS, 256, 0, stream>>>(cnt, partials, N);
    scan_mid<<<1, 256, 0, stream>>>(partials, SCAN_BLOCKS);
    scan_final<<<SCAN_BLOCKS, 256, 0, stream>>>(cnt, row_ptr, partials, N);
    scatter_kernel<<<(E + 255) / 256, 256, 0, stream>>>(edge_src, edge_dst, edge_w,
                                                        cnt, s_edge, flag, E);

    const int CN = 4 * W + 2 * DIM;
    convert_all<<<(CN + 255) / 256, 256, 0, stream>>>(Ws1, Wn1, Ws2, Wn2, b1, b2,
                                                      wcat, flag);

    gather_h0<<<(N * 64 + 255) / 256, 256, 0, stream>>>(node_ids, emb,
                                                        (unsigned int*)h0, flag, N * 64);

    // Layer 1
    agg_kernel<<<(N + 3) / 4, 256, 0, stream>>>((const unsigned int*)h0, row_ptr,
                                                s_edge, (unsigned int*)ngh, N, E);
    gemm_layer<<<(N + 63) / 64, 256, 0, stream>>>(h0, ngh, Ws1c, Wn1c, b1c,
                                                  h1, N, 1, 0, flag);

    // Layer 2
    agg_kernel<<<(N + 3) / 4, 256, 0, stream>>>((const unsigned int*)h1, row_ptr,
                                                s_edge, (unsigned int*)ngh, N, E);
    gemm_layer<<<(N + 63) / 64, 256, 0, stream>>>(h1, ngh, Ws2c, Wn2c, b2c,
                                                  d_out, N, 0, 1, flag);
}

// Round 6
// 267.867 us; speedup vs baseline: 1.8778x; 1.1515x over previous
//
#include <hip/hip_runtime.h>
#include <stdint.h>

// N=50000 nodes, E=600000 edges, D=128.  Edge records pack src into 16 bits
// -> requires N <= 65536 (true here).
#define DIM 128
#define SCAN_BLOCKS 256

typedef __attribute__((ext_vector_type(8))) short bf16x8;
typedef __attribute__((ext_vector_type(4))) float floatx4;

__device__ __forceinline__ float bf2f(unsigned short u) {
    union { unsigned int i; float f; } v; v.i = ((unsigned int)u) << 16; return v.f;
}
__device__ __forceinline__ unsigned short f2bf(float f) {
    union { float f; unsigned int i; } v; v.f = f;
    unsigned int r = (v.i + 0x7FFFu + ((v.i >> 16) & 1u)) >> 16;
    return (unsigned short)r;
}

// Per-block dtype flag: 1 = inputs are fp32, 0 = bf16. Low ushort of each
// 32b word of emb read as bf16 is sane iff the buffer is really bf16.
// Costs 64 L2-hot loads per block. Must be called uniformly by all threads.
__device__ __forceinline__ int block_flag(const unsigned int* __restrict__ emb32) {
    __shared__ int sf;
    if (threadIdx.x < 64) {
        unsigned int v = emb32[threadIdx.x];
        float f = bf2f((unsigned short)(v & 0xffffu));
        int bad = !(fabsf(f) < 1e4f);   // catches NaN too
        unsigned long long m = __ballot(bad);
        if (threadIdx.x == 0) sf = (__popcll(m) > 16) ? 1 : 0;
    }
    __syncthreads();
    return sf;
}

// ---- CSR build ---------------------------------------------------------

__global__ void hist_kernel(const int* __restrict__ dst, int* __restrict__ cnt, int E) {
    int e = blockIdx.x * 256 + threadIdx.x;
    if (e < E) atomicAdd(&cnt[dst[e]], 1);
}

// Phase 1: per-block chunk sums.
__global__ __launch_bounds__(256) void scan_partial(const int* __restrict__ cnt,
                                                    int* __restrict__ partials, int N) {
    int b = blockIdx.x;
    int chunk = (N + gridDim.x - 1) / gridDim.x;
    int beg = b * chunk;
    int end = min(beg + chunk, N);
    int t = threadIdx.x;
    int s = 0;
    for (int i = beg + t; i < end; i += 256) s += cnt[i];
    for (int off = 32; off > 0; off >>= 1) s += __shfl_xor(s, off);
    __shared__ int ws[4];
    if ((t & 63) == 0) ws[t >> 6] = s;
    __syncthreads();
    if (t == 0) partials[b] = ws[0] + ws[1] + ws[2] + ws[3];
}

// Phase 2+3 merged: every block redundantly exclusive-scans the 256
// partials in LDS (cheap), then does its local scan -> row_ptr & cursor.
__global__ __launch_bounds__(256) void scan_final(int* __restrict__ cnt,
                                                  int* __restrict__ row_ptr,
                                                  const int* __restrict__ partials, int N) {
    __shared__ int ptile[256];
    __shared__ int tile[256];
    __shared__ int s_run;
    int t = threadIdx.x;
    int b = blockIdx.x;
    // redundant scan of partials
    int pv = partials[t];
    ptile[t] = pv;
    __syncthreads();
    for (int off = 1; off < 256; off <<= 1) {
        int x = (t >= off) ? ptile[t - off] : 0;
        __syncthreads();
        ptile[t] += x;
        __syncthreads();
    }
    if (t == 0) s_run = (b == 0) ? 0 : 0;   // set below
    if (t == b) s_run = ptile[t] - pv;      // exclusive prefix for block b
    __syncthreads();

    int chunk = (N + gridDim.x - 1) / gridDim.x;
    int beg = b * chunk;
    int end = min(beg + chunk, N);
    for (int base = beg; base < end; base += 256) {
        int i = base + t;
        int v = (i < end) ? cnt[i] : 0;
        tile[t] = v;
        __syncthreads();
        for (int off = 1; off < 256; off <<= 1) {
            int x = (t >= off) ? tile[t - off] : 0;
            __syncthreads();
            tile[t] += x;
            __syncthreads();
        }
        int run = s_run;
        if (i < end) {
            int start = run + tile[t] - v;
            row_ptr[i] = start;
            cnt[i] = start;                 // cursor = row start
            if (i == N - 1) row_ptr[N] = start + v;
        }
        __syncthreads();
        if (t == 255) s_run = run + tile[255];
        __syncthreads();
    }
}

// One packed 4B record per edge: src16 | (w_bf16 << 16).
__global__ __launch_bounds__(256) void scatter_kernel(const int* __restrict__ src,
                               const int* __restrict__ dst,
                               const void* __restrict__ w_any,
                               const unsigned int* __restrict__ emb32,
                               int* __restrict__ cursor,
                               unsigned int* __restrict__ s_edge, int E) {
    int flag = block_flag(emb32);
    int e = blockIdx.x * 256 + threadIdx.x;
    if (e >= E) return;
    unsigned short wb = flag ? f2bf(((const float*)w_any)[e])
                             : ((const unsigned short*)w_any)[e];
    int d = dst[e];
    unsigned int rec = ((unsigned int)src[e] & 0xffffu) | ((unsigned int)wb << 16);
    int pos = atomicAdd(&cursor[d], 1);
    s_edge[pos] = rec;
}

// ---- prep: weight/bias canonicalization + h0 = emb[node_ids] -----------
// blockIdx < conv_blocks: convert Ws1|Wn1|Ws2|Wn2|b1|b2 into wcat arena.
// else: gather h0 rows (bf16-canonical).
__global__ __launch_bounds__(256) void prep_kernel(const void* __restrict__ s0,
                            const void* __restrict__ s1,
                            const void* __restrict__ s2, const void* __restrict__ s3,
                            const void* __restrict__ s4, const void* __restrict__ s5,
                            unsigned short* __restrict__ wcat,
                            const int* __restrict__ ids, const void* __restrict__ emb,
                            unsigned int* __restrict__ h032,
                            int conv_blocks, int total_gather) {
    int flag = block_flag((const unsigned int*)emb);
    const int W = DIM * DIM;
    if ((int)blockIdx.x < conv_blocks) {
        int i = blockIdx.x * 256 + threadIdx.x;
        const void* src; int off;
        if      (i < W)             { src = s0; off = i; }
        else if (i < 2 * W)         { src = s1; off = i - W; }
        else if (i < 3 * W)         { src = s2; off = i - 2 * W; }
        else if (i < 4 * W)         { src = s3; off = i - 3 * W; }
        else if (i < 4 * W + DIM)   { src = s4; off = i - 4 * W; }
        else if (i < 4 * W + 2*DIM) { src = s5; off = i - 4 * W - DIM; }
        else return;
        wcat[i] = flag ? f2bf(((const float*)src)[off])
                       : ((const unsigned short*)src)[off];
    } else {
        int t = (blockIdx.x - conv_blocks) * 256 + threadIdx.x;
        if (t >= total_gather) return;
        int n = t >> 6;           // 64 uints (=128 bf16) per row
        int f = t & 63;
        int id = ids[n];
        unsigned int o;
        if (flag) {
            const float* e = (const float*)emb + (size_t)id * DIM + f * 2;
            o = ((unsigned int)f2bf(e[1]) << 16) | (unsigned int)f2bf(e[0]);
        } else {
            o = ((const unsigned int*)emb)[(size_t)id * 64 + f];
        }
        h032[t] = o;
    }
}

// ---- neighbor mean: one wave per node, unroll x8, scalar record loads ---

__global__ __launch_bounds__(256) void agg_kernel(const unsigned int* __restrict__ h32,
                                                  const int* __restrict__ row_ptr,
                                                  const unsigned int* __restrict__ s_edge,
                                                  unsigned int* __restrict__ out32,
                                                  int N, int E) {
    int node = blockIdx.x * 4 + (threadIdx.x >> 6);
    int lane = threadIdx.x & 63;
    if (node >= N) return;
    // wave-uniform bounds -> record loads become scalar (SMEM path)
    int beg = __builtin_amdgcn_readfirstlane(max(row_ptr[node], 0));
    int end = __builtin_amdgcn_readfirstlane(min(row_ptr[node + 1], E));
    float a0 = 0.f, a1 = 0.f;
    int e = beg;
    for (; e + 8 <= end; e += 8) {
        unsigned int r[8];
        int k[8]; float w[8];
        unsigned int v[8];
#pragma unroll
        for (int i = 0; i < 8; ++i) r[i] = s_edge[e + i];
#pragma unroll
        for (int i = 0; i < 8; ++i) {
            k[i] = min((int)(r[i] & 0xffffu), N - 1);
            w[i] = bf2f((unsigned short)(r[i] >> 16));
        }
#pragma unroll
        for (int i = 0; i < 8; ++i) v[i] = h32[(size_t)k[i] * 64 + lane];
#pragma unroll
        for (int i = 0; i < 8; ++i) {
            a0 += w[i] * bf2f((unsigned short)(v[i] & 0xffffu));
            a1 += w[i] * bf2f((unsigned short)(v[i] >> 16));
        }
    }
    for (; e + 4 <= end; e += 4) {
        unsigned int r[4];
        int k[4]; float w[4];
        unsigned int v[4];
#pragma unroll
        for (int i = 0; i < 4; ++i) r[i] = s_edge[e + i];
#pragma unroll
        for (int i = 0; i < 4; ++i) {
            k[i] = min((int)(r[i] & 0xffffu), N - 1);
            w[i] = bf2f((unsigned short)(r[i] >> 16));
        }
#pragma unroll
        for (int i = 0; i < 4; ++i) v[i] = h32[(size_t)k[i] * 64 + lane];
#pragma unroll
        for (int i = 0; i < 4; ++i) {
            a0 += w[i] * bf2f((unsigned short)(v[i] & 0xffffu));
            a1 += w[i] * bf2f((unsigned short)(v[i] >> 16));
        }
    }
    for (; e < end; ++e) {
        unsigned int r = s_edge[e];
        int k = min((int)(r & 0xffffu), N - 1);
        float w = bf2f((unsigned short)(r >> 16));
        unsigned int v = h32[(size_t)k * 64 + lane];
        a0 += w * bf2f((unsigned short)(v & 0xffffu));
        a1 += w * bf2f((unsigned short)(v >> 16));
    }
    float inv = (end > beg) ? 1.0f / (float)(end - beg) : 0.f;
    a0 *= inv; a1 *= inv;
    unsigned int o = ((unsigned int)f2bf(a1) << 16) | (unsigned int)f2bf(a0);
    out32[(size_t)node * 64 + lane] = o;
}

// ---- fused SAGE linear: out = h @ Wself^T + b + neigh @ Wneigh^T (+relu)
// MFMA 16x16x32 bf16. Block = 4 waves; each wave computes 32 rows x 128
// cols (2 row-tiles share every B fragment -> half the B traffic of 16).
// A frag: lane holds A[m=lane&15][k=quad*8+j]; B frag: W[n=lane&15][k=quad*8+j]
// C/D: D[row=quad*4+r][col=lane&15]

__global__ __launch_bounds__(256) void gemm_layer(const unsigned short* __restrict__ A0,
                                                  const unsigned short* __restrict__ A1,
                                                  const unsigned short* __restrict__ W0,
                                                  const unsigned short* __restrict__ W1,
                                                  const unsigned short* __restrict__ bias,
                                                  void* __restrict__ out,
                                                  const unsigned int* __restrict__ emb32,
                                                  int n_rows, int relu, int is_final) {
    int fp32_out = is_final ? block_flag(emb32) : (void(block_flag(emb32)), 0);
    int wave = threadIdx.x >> 6;
    int lane = threadIdx.x & 63;
    int quad = lane >> 4;
    int l16  = lane & 15;
    int m_base = blockIdx.x * 128 + wave * 32;

    floatx4 acc0[8], acc1[8];
#pragma unroll
    for (int c = 0; c < 8; ++c) {
        acc0[c] = (floatx4){0.f, 0.f, 0.f, 0.f};
        acc1[c] = (floatx4){0.f, 0.f, 0.f, 0.f};
    }

    int r0 = min(m_base + l16, n_rows - 1);        // clamp; stores guarded
    int r1 = min(m_base + 16 + l16, n_rows - 1);

#pragma unroll
    for (int mat = 0; mat < 2; ++mat) {
        const unsigned short* A  = mat ? A1 : A0;
        const unsigned short* Wm = mat ? W1 : W0;
        const unsigned short* Ar0 = A + (size_t)r0 * DIM;
        const unsigned short* Ar1 = A + (size_t)r1 * DIM;
#pragma unroll
        for (int ks = 0; ks < 4; ++ks) {
            int k0 = ks * 32 + quad * 8;
            bf16x8 a0 = *(const bf16x8*)(Ar0 + k0);
            bf16x8 a1 = *(const bf16x8*)(Ar1 + k0);
#pragma unroll
            for (int c = 0; c < 8; ++c) {
                bf16x8 b = *(const bf16x8*)(Wm + (size_t)(c * 16 + l16) * DIM + k0);
                acc0[c] = __builtin_amdgcn_mfma_f32_16x16x32_bf16(a0, b, acc0[c], 0, 0, 0);
                acc1[c] = __builtin_amdgcn_mfma_f32_16x16x32_bf16(a1, b, acc1[c], 0, 0, 0);
            }
        }
    }

#pragma unroll
    for (int c = 0; c < 8; ++c) {
        int col = c * 16 + l16;
        float bv = bf2f(bias[col]);
#pragma unroll
        for (int r = 0; r < 4; ++r) {
            int row0 = m_base + quad * 4 + r;
            int row1 = row0 + 16;
            if (row0 < n_rows) {
                float v = acc0[c][r] + bv;
                if (relu) v = fmaxf(v, 0.f);
                size_t idx = (size_t)row0 * DIM + col;
                if (fp32_out) ((float*)out)[idx] = v;
                else          ((unsigned short*)out)[idx] = f2bf(v);
            }
            if (row1 < n_rows) {
                float v = acc1[c][r] + bv;
                if (relu) v = fmaxf(v, 0.f);
                size_t idx = (size_t)row1 * DIM + col;
                if (fp32_out) ((float*)out)[idx] = v;
                else          ((unsigned short*)out)[idx] = f2bf(v);
            }
        }
    }
}

// ---- launch ------------------------------------------------------------

extern "C" void kernel_launch(void* const* d_in, const int* in_sizes, int n_in,
                              void* d_out, int out_size, void* d_ws, size_t ws_size,
                              hipStream_t stream) {
    const int* node_ids = (const int*)d_in[0];
    const int* edge_src = (const int*)d_in[1];
    const int* edge_dst = (const int*)d_in[2];
    const void* edge_w  = d_in[3];
    const void* emb     = d_in[4];
    const void* Ws1     = d_in[5];
    const void* Wn1     = d_in[6];
    const void* b1      = d_in[7];
    const void* Ws2     = d_in[8];
    const void* Wn2     = d_in[9];
    const void* b2      = d_in[10];

    const int N = in_sizes[0];
    const int E = in_sizes[1];

    char* w = (char*)d_ws;
    auto alloc = [&](size_t bytes) {
        char* p = w;
        w += (bytes + 255) & ~(size_t)255;
        return p;
    };
    int* partials       = (int*)alloc((size_t)SCAN_BLOCKS * 4);
    int* row_ptr        = (int*)alloc((size_t)(N + 1) * 4);
    int* cnt            = (int*)alloc((size_t)N * 4);
    const int W = DIM * DIM;
    unsigned short* wcat = (unsigned short*)alloc((size_t)(4 * W + 2 * DIM) * 2);
    unsigned short* Ws1c = wcat;
    unsigned short* Wn1c = wcat + W;
    unsigned short* Ws2c = wcat + 2 * W;
    unsigned short* Wn2c = wcat + 3 * W;
    unsigned short* b1c  = wcat + 4 * W;
    unsigned short* b2c  = wcat + 4 * W + DIM;
    unsigned int* s_edge = (unsigned int*)alloc((size_t)E * 4);
    unsigned short* h0  = (unsigned short*)alloc((size_t)N * DIM * 2);
    unsigned short* h1  = (unsigned short*)alloc((size_t)N * DIM * 2);
    unsigned short* ngh = (unsigned short*)alloc((size_t)N * DIM * 2);

    const unsigned int* emb32 = (const unsigned int*)emb;

    hipMemsetAsync(cnt, 0, (size_t)N * 4, stream);
    hist_kernel<<<(E + 255) / 256, 256, 0, stream>>>(edge_dst, cnt, E);
    scan_partial<<<SCAN_BLOCKS, 256, 0, stream>>>(cnt, partials, N);
    scan_final<<<SCAN_BLOCKS, 256, 0, stream>>>(cnt, row_ptr, partials, N);
    scatter_kernel<<<(E + 255) / 256, 256, 0, stream>>>(edge_src, edge_dst, edge_w,
                                                        emb32, cnt, s_edge, E);

    const int CN = 4 * W + 2 * DIM;
    const int conv_blocks = (CN + 255) / 256;
    const int gather_total = N * 64;
    const int gather_blocks = (gather_total + 255) / 256;
    prep_kernel<<<conv_blocks + gather_blocks, 256, 0, stream>>>(
        Ws1, Wn1, Ws2, Wn2, b1, b2, wcat, node_ids, emb,
        (unsigned int*)h0, conv_blocks, gather_total);

    // Layer 1
    agg_kernel<<<(N + 3) / 4, 256, 0, stream>>>((const unsigned int*)h0, row_ptr,
                                                s_edge, (unsigned int*)ngh, N, E);
    gemm_layer<<<(N + 127) / 128, 256, 0, stream>>>(h0, ngh, Ws1c, Wn1c, b1c,
                                                    h1, emb32, N, 1, 0);

    // Layer 2
    agg_kernel<<<(N + 3) / 4, 256, 0, stream>>>((const unsigned int*)h1, row_ptr,
                                                s_edge, (unsigned int*)ngh, N, E);
    gemm_layer<<<(N + 127) / 128, 256, 0, stream>>>(h1, ngh, Ws2c, Wn2c, b2c,
                                                    d_out, emb32, N, 0, 1);
}

// Round 7
// 265.347 us; speedup vs baseline: 1.8956x; 1.0095x over previous
//
#include <hip/hip_runtime.h>
#include <stdint.h>

// N=50000 nodes, E=600000 edges, D=128.  Edge records pack src into 16 bits
// -> requires N <= 65536 (true here).
#define DIM 128
#define SCAN_BLOCKS 256

typedef __attribute__((ext_vector_type(8))) short bf16x8;
typedef __attribute__((ext_vector_type(4))) float floatx4;

__device__ __forceinline__ float bf2f(unsigned short u) {
    union { unsigned int i; float f; } v; v.i = ((unsigned int)u) << 16; return v.f;
}
__device__ __forceinline__ unsigned short f2bf(float f) {
    union { float f; unsigned int i; } v; v.f = f;
    unsigned int r = (v.i + 0x7FFFu + ((v.i >> 16) & 1u)) >> 16;
    return (unsigned short)r;
}

// Per-block dtype flag: 1 = inputs are fp32, 0 = bf16.
__device__ __forceinline__ int block_flag(const unsigned int* __restrict__ emb32) {
    __shared__ int sf;
    if (threadIdx.x < 64) {
        unsigned int v = emb32[threadIdx.x];
        float f = bf2f((unsigned short)(v & 0xffffu));
        int bad = !(fabsf(f) < 1e4f);   // catches NaN too
        unsigned long long m = __ballot(bad);
        if (threadIdx.x == 0) sf = (__popcll(m) > 16) ? 1 : 0;
    }
    __syncthreads();
    return sf;
}

// ---- CSR build ---------------------------------------------------------

__global__ void hist_kernel(const int* __restrict__ dst, int* __restrict__ cnt, int E) {
    int base = (blockIdx.x * 256 + threadIdx.x) * 4;
#pragma unroll
    for (int i = 0; i < 4; ++i) {
        int e = base + i;
        if (e < E) atomicAdd(&cnt[dst[e]], 1);
    }
}

// Phase 1: per-block chunk sums.
__global__ __launch_bounds__(256) void scan_partial(const int* __restrict__ cnt,
                                                    int* __restrict__ partials, int N) {
    int b = blockIdx.x;
    int chunk = (N + gridDim.x - 1) / gridDim.x;
    int beg = b * chunk;
    int end = min(beg + chunk, N);
    int t = threadIdx.x;
    int s = 0;
    for (int i = beg + t; i < end; i += 256) s += cnt[i];
    for (int off = 32; off > 0; off >>= 1) s += __shfl_xor(s, off);
    __shared__ int ws[4];
    if ((t & 63) == 0) ws[t >> 6] = s;
    __syncthreads();
    if (t == 0) partials[b] = ws[0] + ws[1] + ws[2] + ws[3];
}

// Phase 2+3 merged: every block redundantly exclusive-scans the 256
// partials in LDS, then does its local scan -> row_ptr & cursor.
__global__ __launch_bounds__(256) void scan_final(int* __restrict__ cnt,
                                                  int* __restrict__ row_ptr,
                                                  const int* __restrict__ partials, int N) {
    __shared__ int ptile[256];
    __shared__ int tile[256];
    __shared__ int s_run;
    int t = threadIdx.x;
    int b = blockIdx.x;
    int pv = partials[t];
    ptile[t] = pv;
    __syncthreads();
    for (int off = 1; off < 256; off <<= 1) {
        int x = (t >= off) ? ptile[t - off] : 0;
        __syncthreads();
        ptile[t] += x;
        __syncthreads();
    }
    if (t == b) s_run = ptile[t] - pv;      // exclusive prefix for block b
    __syncthreads();

    int chunk = (N + gridDim.x - 1) / gridDim.x;
    int beg = b * chunk;
    int end = min(beg + chunk, N);
    for (int base = beg; base < end; base += 256) {
        int i = base + t;
        int v = (i < end) ? cnt[i] : 0;
        tile[t] = v;
        __syncthreads();
        for (int off = 1; off < 256; off <<= 1) {
            int x = (t >= off) ? tile[t - off] : 0;
            __syncthreads();
            tile[t] += x;
            __syncthreads();
        }
        int run = s_run;
        if (i < end) {
            int start = run + tile[t] - v;
            row_ptr[i] = start;
            cnt[i] = start;                 // cursor = row start
            if (i == N - 1) row_ptr[N] = start + v;
        }
        __syncthreads();
        if (t == 255) s_run = run + tile[255];
        __syncthreads();
    }
}

// ---- merged scatter + weight-convert + h0-gather -----------------------
// blockIdx < scat_blocks            : scatter packed edge records
// blockIdx < scat_blocks+conv_blocks: convert Ws1|Wn1|Ws2|Wn2|b1|b2 -> wcat
// else                              : gather h0 = emb[node_ids] (bf16)
__global__ __launch_bounds__(256) void scatter_prep_kernel(
        const int* __restrict__ src, const int* __restrict__ dst,
        const void* __restrict__ w_any,
        int* __restrict__ cursor, unsigned int* __restrict__ s_edge, int E,
        const void* __restrict__ s0, const void* __restrict__ s1,
        const void* __restrict__ s2, const void* __restrict__ s3,
        const void* __restrict__ s4, const void* __restrict__ s5,
        unsigned short* __restrict__ wcat,
        const int* __restrict__ ids, const void* __restrict__ emb,
        unsigned int* __restrict__ h032,
        int scat_blocks, int conv_blocks, int total_gather) {
    int flag = block_flag((const unsigned int*)emb);
    const int W = DIM * DIM;
    int blk = (int)blockIdx.x;
    if (blk < scat_blocks) {
        int e = blk * 256 + threadIdx.x;
        if (e >= E) return;
        unsigned short wb = flag ? f2bf(((const float*)w_any)[e])
                                 : ((const unsigned short*)w_any)[e];
        int d = dst[e];
        unsigned int rec = ((unsigned int)src[e] & 0xffffu) | ((unsigned int)wb << 16);
        int pos = atomicAdd(&cursor[d], 1);
        s_edge[pos] = rec;
    } else if (blk < scat_blocks + conv_blocks) {
        int i = (blk - scat_blocks) * 256 + threadIdx.x;
        const void* srcp; int off;
        if      (i < W)             { srcp = s0; off = i; }
        else if (i < 2 * W)         { srcp = s1; off = i - W; }
        else if (i < 3 * W)         { srcp = s2; off = i - 2 * W; }
        else if (i < 4 * W)         { srcp = s3; off = i - 3 * W; }
        else if (i < 4 * W + DIM)   { srcp = s4; off = i - 4 * W; }
        else if (i < 4 * W + 2*DIM) { srcp = s5; off = i - 4 * W - DIM; }
        else return;
        wcat[i] = flag ? f2bf(((const float*)srcp)[off])
                       : ((const unsigned short*)srcp)[off];
    } else {
        int t = (blk - scat_blocks - conv_blocks) * 256 + threadIdx.x;
        if (t >= total_gather) return;
        int n = t >> 6;           // 64 uints (=128 bf16) per row
        int f = t & 63;
        int id = ids[n];
        unsigned int o;
        if (flag) {
            const float* e = (const float*)emb + (size_t)id * DIM + f * 2;
            o = ((unsigned int)f2bf(e[1]) << 16) | (unsigned int)f2bf(e[0]);
        } else {
            o = ((const unsigned int*)emb)[(size_t)id * 64 + f];
        }
        h032[t] = o;
    }
}

// ---- neighbor mean: TWO nodes per wave (half-wave x uint2), unroll x8 ---
// Each 32-lane half covers one 256B row: 8B/lane. 2x bytes in flight per
// wave vs the one-node/4B version at the same wave count.

__global__ __launch_bounds__(256) void agg_kernel(const uint2* __restrict__ h64,
                                                  const int* __restrict__ row_ptr,
                                                  const unsigned int* __restrict__ s_edge,
                                                  uint2* __restrict__ out64,
                                                  int N, int E) {
    int lane = threadIdx.x & 63;
    int half = lane >> 5;       // 0 or 1
    int sub  = lane & 31;       // position within the row (uint2 granularity)
    int node = blockIdx.x * 8 + (threadIdx.x >> 6) * 2 + half;
    if (node >= N) return;
    int beg = max(row_ptr[node], 0);
    int end = min(row_ptr[node + 1], E);
    float a0 = 0.f, a1 = 0.f, a2 = 0.f, a3 = 0.f;
    int e = beg;
    for (; e + 8 <= end; e += 8) {
        unsigned int r[8]; int k[8]; float w[8]; uint2 v[8];
#pragma unroll
        for (int i = 0; i < 8; ++i) r[i] = s_edge[e + i];
#pragma unroll
        for (int i = 0; i < 8; ++i) {
            k[i] = min((int)(r[i] & 0xffffu), N - 1);
            w[i] = bf2f((unsigned short)(r[i] >> 16));
        }
#pragma unroll
        for (int i = 0; i < 8; ++i) v[i] = h64[(size_t)k[i] * 32 + sub];
#pragma unroll
        for (int i = 0; i < 8; ++i) {
            a0 += w[i] * bf2f((unsigned short)(v[i].x & 0xffffu));
            a1 += w[i] * bf2f((unsigned short)(v[i].x >> 16));
            a2 += w[i] * bf2f((unsigned short)(v[i].y & 0xffffu));
            a3 += w[i] * bf2f((unsigned short)(v[i].y >> 16));
        }
    }
    for (; e + 4 <= end; e += 4) {
        unsigned int r[4]; int k[4]; float w[4]; uint2 v[4];
#pragma unroll
        for (int i = 0; i < 4; ++i) r[i] = s_edge[e + i];
#pragma unroll
        for (int i = 0; i < 4; ++i) {
            k[i] = min((int)(r[i] & 0xffffu), N - 1);
            w[i] = bf2f((unsigned short)(r[i] >> 16));
        }
#pragma unroll
        for (int i = 0; i < 4; ++i) v[i] = h64[(size_t)k[i] * 32 + sub];
#pragma unroll
        for (int i = 0; i < 4; ++i) {
            a0 += w[i] * bf2f((unsigned short)(v[i].x & 0xffffu));
            a1 += w[i] * bf2f((unsigned short)(v[i].x >> 16));
            a2 += w[i] * bf2f((unsigned short)(v[i].y & 0xffffu));
            a3 += w[i] * bf2f((unsigned short)(v[i].y >> 16));
        }
    }
    for (; e < end; ++e) {
        unsigned int r = s_edge[e];
        int k = min((int)(r & 0xffffu), N - 1);
        float w = bf2f((unsigned short)(r >> 16));
        uint2 v = h64[(size_t)k * 32 + sub];
        a0 += w * bf2f((unsigned short)(v.x & 0xffffu));
        a1 += w * bf2f((unsigned short)(v.x >> 16));
        a2 += w * bf2f((unsigned short)(v.y & 0xffffu));
        a3 += w * bf2f((unsigned short)(v.y >> 16));
    }
    float inv = (end > beg) ? 1.0f / (float)(end - beg) : 0.f;
    a0 *= inv; a1 *= inv; a2 *= inv; a3 *= inv;
    uint2 o;
    o.x = ((unsigned int)f2bf(a1) << 16) | (unsigned int)f2bf(a0);
    o.y = ((unsigned int)f2bf(a3) << 16) | (unsigned int)f2bf(a2);
    out64[(size_t)node * 32 + sub] = o;
}

// ---- fused SAGE linear: out = h @ Wself^T + b + neigh @ Wneigh^T (+relu)
// MFMA 16x16x32 bf16. Block = 4 waves; each wave computes 32 rows x 128
// cols (2 row-tiles share every B fragment).
// A frag: lane holds A[m=lane&15][k=quad*8+j]; B frag: W[n=lane&15][k=quad*8+j]
// C/D: D[row=quad*4+r][col=lane&15]

__global__ __launch_bounds__(256) void gemm_layer(const unsigned short* __restrict__ A0,
                                                  const unsigned short* __restrict__ A1,
                                                  const unsigned short* __restrict__ W0,
                                                  const unsigned short* __restrict__ W1,
                                                  const unsigned short* __restrict__ bias,
                                                  void* __restrict__ out,
                                                  const unsigned int* __restrict__ emb32,
                                                  int n_rows, int relu, int is_final) {
    int fp32_out = is_final ? block_flag(emb32) : (void(block_flag(emb32)), 0);
    int wave = threadIdx.x >> 6;
    int lane = threadIdx.x & 63;
    int quad = lane >> 4;
    int l16  = lane & 15;
    int m_base = blockIdx.x * 128 + wave * 32;

    floatx4 acc0[8], acc1[8];
#pragma unroll
    for (int c = 0; c < 8; ++c) {
        acc0[c] = (floatx4){0.f, 0.f, 0.f, 0.f};
        acc1[c] = (floatx4){0.f, 0.f, 0.f, 0.f};
    }

    int r0 = min(m_base + l16, n_rows - 1);        // clamp; stores guarded
    int r1 = min(m_base + 16 + l16, n_rows - 1);

#pragma unroll
    for (int mat = 0; mat < 2; ++mat) {
        const unsigned short* A  = mat ? A1 : A0;
        const unsigned short* Wm = mat ? W1 : W0;
        const unsigned short* Ar0 = A + (size_t)r0 * DIM;
        const unsigned short* Ar1 = A + (size_t)r1 * DIM;
#pragma unroll
        for (int ks = 0; ks < 4; ++ks) {
            int k0 = ks * 32 + quad * 8;
            bf16x8 a0 = *(const bf16x8*)(Ar0 + k0);
            bf16x8 a1 = *(const bf16x8*)(Ar1 + k0);
#pragma unroll
            for (int c = 0; c < 8; ++c) {
                bf16x8 b = *(const bf16x8*)(Wm + (size_t)(c * 16 + l16) * DIM + k0);
                acc0[c] = __builtin_amdgcn_mfma_f32_16x16x32_bf16(a0, b, acc0[c], 0, 0, 0);
                acc1[c] = __builtin_amdgcn_mfma_f32_16x16x32_bf16(a1, b, acc1[c], 0, 0, 0);
            }
        }
    }

#pragma unroll
    for (int c = 0; c < 8; ++c) {
        int col = c * 16 + l16;
        float bv = bf2f(bias[col]);
#pragma unroll
        for (int r = 0; r < 4; ++r) {
            int row0 = m_base + quad * 4 + r;
            int row1 = row0 + 16;
            if (row0 < n_rows) {
                float v = acc0[c][r] + bv;
                if (relu) v = fmaxf(v, 0.f);
                size_t idx = (size_t)row0 * DIM + col;
                if (fp32_out) ((float*)out)[idx] = v;
                else          ((unsigned short*)out)[idx] = f2bf(v);
            }
            if (row1 < n_rows) {
                float v = acc1[c][r] + bv;
                if (relu) v = fmaxf(v, 0.f);
                size_t idx = (size_t)row1 * DIM + col;
                if (fp32_out) ((float*)out)[idx] = v;
                else          ((unsigned short*)out)[idx] = f2bf(v);
            }
        }
    }
}

// ---- launch ------------------------------------------------------------

extern "C" void kernel_launch(void* const* d_in, const int* in_sizes, int n_in,
                              void* d_out, int out_size, void* d_ws, size_t ws_size,
                              hipStream_t stream) {
    const int* node_ids = (const int*)d_in[0];
    const int* edge_src = (const int*)d_in[1];
    const int* edge_dst = (const int*)d_in[2];
    const void* edge_w  = d_in[3];
    const void* emb     = d_in[4];
    const void* Ws1     = d_in[5];
    const void* Wn1     = d_in[6];
    const void* b1      = d_in[7];
    const void* Ws2     = d_in[8];
    const void* Wn2     = d_in[9];
    const void* b2      = d_in[10];

    const int N = in_sizes[0];
    const int E = in_sizes[1];

    char* w = (char*)d_ws;
    auto alloc = [&](size_t bytes) {
        char* p = w;
        w += (bytes + 255) & ~(size_t)255;
        return p;
    };
    int* partials       = (int*)alloc((size_t)SCAN_BLOCKS * 4);
    int* row_ptr        = (int*)alloc((size_t)(N + 1) * 4);
    int* cnt            = (int*)alloc((size_t)N * 4);
    const int W = DIM * DIM;
    unsigned short* wcat = (unsigned short*)alloc((size_t)(4 * W + 2 * DIM) * 2);
    unsigned short* Ws1c = wcat;
    unsigned short* Wn1c = wcat + W;
    unsigned short* Ws2c = wcat + 2 * W;
    unsigned short* Wn2c = wcat + 3 * W;
    unsigned short* b1c  = wcat + 4 * W;
    unsigned short* b2c  = wcat + 4 * W + DIM;
    unsigned int* s_edge = (unsigned int*)alloc((size_t)E * 4);
    unsigned short* h0  = (unsigned short*)alloc((size_t)N * DIM * 2);
    unsigned short* h1  = (unsigned short*)alloc((size_t)N * DIM * 2);
    unsigned short* ngh = (unsigned short*)alloc((size_t)N * DIM * 2);

    const unsigned int* emb32 = (const unsigned int*)emb;

    hipMemsetAsync(cnt, 0, (size_t)N * 4, stream);
    hist_kernel<<<(E + 1023) / 1024, 256, 0, stream>>>(edge_dst, cnt, E);
    scan_partial<<<SCAN_BLOCKS, 256, 0, stream>>>(cnt, partials, N);
    scan_final<<<SCAN_BLOCKS, 256, 0, stream>>>(cnt, row_ptr, partials, N);

    const int CN = 4 * W + 2 * DIM;
    const int scat_blocks = (E + 255) / 256;
    const int conv_blocks = (CN + 255) / 256;
    const int gather_total = N * 64;
    const int gather_blocks = (gather_total + 255) / 256;
    scatter_prep_kernel<<<scat_blocks + conv_blocks + gather_blocks, 256, 0, stream>>>(
        edge_src, edge_dst, edge_w, cnt, s_edge, E,
        Ws1, Wn1, Ws2, Wn2, b1, b2, wcat, node_ids, emb,
        (unsigned int*)h0, scat_blocks, conv_blocks, gather_total);

    // Layer 1
    agg_kernel<<<(N + 7) / 8, 256, 0, stream>>>((const uint2*)h0, row_ptr,
                                                s_edge, (uint2*)ngh, N, E);
    gemm_layer<<<(N + 127) / 128, 256, 0, stream>>>(h0, ngh, Ws1c, Wn1c, b1c,
                                                    h1, emb32, N, 1, 0);

    // Layer 2
    agg_kernel<<<(N + 7) / 8, 256, 0, stream>>>((const uint2*)h1, row_ptr,
                                                s_edge, (uint2*)ngh, N, E);
    gemm_layer<<<(N + 127) / 128, 256, 0, stream>>>(h1, ngh, Ws2c, Wn2c, b2c,
                                                    d_out, emb32, N, 0, 1);
}

// Round 9
// 245.721 us; speedup vs baseline: 2.0470x; 1.0799x over previous
//
#include <hip/hip_runtime.h>
#include <stdint.h>

// N=50000 nodes, E=600000 edges, D=128.  Edge records pack src into 16 bits
// -> requires N <= 65536 (true here).
#define DIM 128
#define SCAN_BLOCKS 256
#define CP 16   // cursor padding: one counter per 64B line (atomic-unit spread)

typedef __attribute__((ext_vector_type(8))) short bf16x8;
typedef __attribute__((ext_vector_type(4))) float floatx4;

__device__ __forceinline__ float bf2f(unsigned short u) {
    union { unsigned int i; float f; } v; v.i = ((unsigned int)u) << 16; return v.f;
}
__device__ __forceinline__ unsigned short f2bf(float f) {
    union { float f; unsigned int i; } v; v.f = f;
    unsigned int r = (v.i + 0x7FFFu + ((v.i >> 16) & 1u)) >> 16;
    return (unsigned short)r;
}

// Per-block dtype flag: 1 = inputs are fp32, 0 = bf16.
__device__ __forceinline__ int block_flag(const unsigned int* __restrict__ emb32) {
    __shared__ int sf;
    if (threadIdx.x < 64) {
        unsigned int v = emb32[threadIdx.x];
        float f = bf2f((unsigned short)(v & 0xffffu));
        int bad = !(fabsf(f) < 1e4f);   // catches NaN too
        unsigned long long m = __ballot(bad);
        if (threadIdx.x == 0) sf = (__popcll(m) > 16) ? 1 : 0;
    }
    __syncthreads();
    return sf;
}

// ---- CSR build ---------------------------------------------------------

__global__ void hist_kernel(const int* __restrict__ dst, int* __restrict__ cnt, int E) {
    int base = (blockIdx.x * 256 + threadIdx.x) * 4;
#pragma unroll
    for (int i = 0; i < 4; ++i) {
        int e = base + i;
        if (e < E) atomicAdd(&cnt[dst[e] * CP], 1);
    }
}

// Phase 1: per-block chunk sums (cnt strided by CP).
__global__ __launch_bounds__(256) void scan_partial(const int* __restrict__ cnt,
                                                    int* __restrict__ partials, int N) {
    int b = blockIdx.x;
    int chunk = (N + gridDim.x - 1) / gridDim.x;
    int beg = b * chunk;
    int end = min(beg + chunk, N);
    int t = threadIdx.x;
    int s = 0;
    for (int i = beg + t; i < end; i += 256) s += cnt[i * CP];
    for (int off = 32; off > 0; off >>= 1) s += __shfl_xor(s, off);
    __shared__ int ws[4];
    if ((t & 63) == 0) ws[t >> 6] = s;
    __syncthreads();
    if (t == 0) partials[b] = ws[0] + ws[1] + ws[2] + ws[3];
}

// Phase 2+3 merged: every block redundantly exclusive-scans the 256
// partials in LDS, then local scan -> row_ptr & padded cursor.
__global__ __launch_bounds__(256) void scan_final(int* __restrict__ cnt,
                                                  int* __restrict__ row_ptr,
                                                  const int* __restrict__ partials, int N) {
    __shared__ int ptile[256];
    __shared__ int tile[256];
    __shared__ int s_run;
    int t = threadIdx.x;
    int b = blockIdx.x;
    int pv = partials[t];
    ptile[t] = pv;
    __syncthreads();
    for (int off = 1; off < 256; off <<= 1) {
        int x = (t >= off) ? ptile[t - off] : 0;
        __syncthreads();
        ptile[t] += x;
        __syncthreads();
    }
    if (t == b) s_run = ptile[t] - pv;      // exclusive prefix for block b
    __syncthreads();

    int chunk = (N + gridDim.x - 1) / gridDim.x;
    int beg = b * chunk;
    int end = min(beg + chunk, N);
    for (int base = beg; base < end; base += 256) {
        int i = base + t;
        int v = (i < end) ? cnt[i * CP] : 0;
        tile[t] = v;
        __syncthreads();
        for (int off = 1; off < 256; off <<= 1) {
            int x = (t >= off) ? tile[t - off] : 0;
            __syncthreads();
            tile[t] += x;
            __syncthreads();
        }
        int run = s_run;
        if (i < end) {
            int start = run + tile[t] - v;
            row_ptr[i] = start;
            cnt[i * CP] = start;            // cursor = row start
            if (i == N - 1) row_ptr[N] = start + v;
        }
        __syncthreads();
        if (t == 255) s_run = run + tile[255];
        __syncthreads();
    }
}

// ---- merged scatter + weight-convert + h0-gather -----------------------
__global__ __launch_bounds__(256) void scatter_prep_kernel(
        const int* __restrict__ src, const int* __restrict__ dst,
        const void* __restrict__ w_any,
        int* __restrict__ cursor, unsigned int* __restrict__ s_edge, int E,
        const void* __restrict__ s0, const void* __restrict__ s1,
        const void* __restrict__ s2, const void* __restrict__ s3,
        const void* __restrict__ s4, const void* __restrict__ s5,
        unsigned short* __restrict__ wcat,
        const int* __restrict__ ids, const void* __restrict__ emb,
        unsigned int* __restrict__ h032,
        int scat_blocks, int conv_blocks, int total_gather) {
    int flag = block_flag((const unsigned int*)emb);
    const int W = DIM * DIM;
    int blk = (int)blockIdx.x;
    if (blk < scat_blocks) {
        int e = blk * 256 + threadIdx.x;
        if (e >= E) return;
        unsigned short wb = flag ? f2bf(((const float*)w_any)[e])
                                 : ((const unsigned short*)w_any)[e];
        int d = dst[e];
        unsigned int rec = ((unsigned int)src[e] & 0xffffu) | ((unsigned int)wb << 16);
        int pos = atomicAdd(&cursor[d * CP], 1);
        __builtin_nontemporal_store(rec, &s_edge[pos]);
    } else if (blk < scat_blocks + conv_blocks) {
        int i = (blk - scat_blocks) * 256 + threadIdx.x;
        const void* srcp; int off;
        if      (i < W)             { srcp = s0; off = i; }
        else if (i < 2 * W)         { srcp = s1; off = i - W; }
        else if (i < 3 * W)         { srcp = s2; off = i - 2 * W; }
        else if (i < 4 * W)         { srcp = s3; off = i - 3 * W; }
        else if (i < 4 * W + DIM)   { srcp = s4; off = i - 4 * W; }
        else if (i < 4 * W + 2*DIM) { srcp = s5; off = i - 4 * W - DIM; }
        else return;
        wcat[i] = flag ? f2bf(((const float*)srcp)[off])
                       : ((const unsigned short*)srcp)[off];
    } else {
        int t = (blk - scat_blocks - conv_blocks) * 256 + threadIdx.x;
        if (t >= total_gather) return;
        int n = t >> 6;           // 64 uints (=128 bf16) per row
        int f = t & 63;
        int id = ids[n];
        unsigned int o;
        if (flag) {
            const float* e = (const float*)emb + (size_t)id * DIM + f * 2;
            o = ((unsigned int)f2bf(e[1]) << 16) | (unsigned int)f2bf(e[0]);
        } else {
            o = ((const unsigned int*)emb)[(size_t)id * 64 + f];
        }
        h032[t] = o;
    }
}

// ---- neighbor mean: TWO nodes per wave (half-wave x uint2), unroll x8 ---

__global__ __launch_bounds__(256) void agg_kernel(const uint2* __restrict__ h64,
                                                  const int* __restrict__ row_ptr,
                                                  const unsigned int* __restrict__ s_edge,
                                                  uint2* __restrict__ out64,
                                                  int N, int E) {
    int lane = threadIdx.x & 63;
    int half = lane >> 5;       // 0 or 1
    int sub  = lane & 31;       // position within the row (uint2 granularity)
    int node = blockIdx.x * 8 + (threadIdx.x >> 6) * 2 + half;
    if (node >= N) return;
    int beg = max(row_ptr[node], 0);
    int end = min(row_ptr[node + 1], E);
    float a0 = 0.f, a1 = 0.f, a2 = 0.f, a3 = 0.f;
    int e = beg;
    for (; e + 8 <= end; e += 8) {
        unsigned int r[8]; int k[8]; float w[8]; uint2 v[8];
#pragma unroll
        for (int i = 0; i < 8; ++i) r[i] = s_edge[e + i];
#pragma unroll
        for (int i = 0; i < 8; ++i) {
            k[i] = min((int)(r[i] & 0xffffu), N - 1);
            w[i] = bf2f((unsigned short)(r[i] >> 16));
        }
#pragma unroll
        for (int i = 0; i < 8; ++i) v[i] = h64[(size_t)k[i] * 32 + sub];
#pragma unroll
        for (int i = 0; i < 8; ++i) {
            a0 += w[i] * bf2f((unsigned short)(v[i].x & 0xffffu));
            a1 += w[i] * bf2f((unsigned short)(v[i].x >> 16));
            a2 += w[i] * bf2f((unsigned short)(v[i].y & 0xffffu));
            a3 += w[i] * bf2f((unsigned short)(v[i].y >> 16));
        }
    }
    for (; e + 4 <= end; e += 4) {
        unsigned int r[4]; int k[4]; float w[4]; uint2 v[4];
#pragma unroll
        for (int i = 0; i < 4; ++i) r[i] = s_edge[e + i];
#pragma unroll
        for (int i = 0; i < 4; ++i) {
            k[i] = min((int)(r[i] & 0xffffu), N - 1);
            w[i] = bf2f((unsigned short)(r[i] >> 16));
        }
#pragma unroll
        for (int i = 0; i < 4; ++i) v[i] = h64[(size_t)k[i] * 32 + sub];
#pragma unroll
        for (int i = 0; i < 4; ++i) {
            a0 += w[i] * bf2f((unsigned short)(v[i].x & 0xffffu));
            a1 += w[i] * bf2f((unsigned short)(v[i].x >> 16));
            a2 += w[i] * bf2f((unsigned short)(v[i].y & 0xffffu));
            a3 += w[i] * bf2f((unsigned short)(v[i].y >> 16));
        }
    }
    for (; e < end; ++e) {
        unsigned int r = s_edge[e];
        int k = min((int)(r & 0xffffu), N - 1);
        float w = bf2f((unsigned short)(r >> 16));
        uint2 v = h64[(size_t)k * 32 + sub];
        a0 += w * bf2f((unsigned short)(v.x & 0xffffu));
        a1 += w * bf2f((unsigned short)(v.x >> 16));
        a2 += w * bf2f((unsigned short)(v.y & 0xffffu));
        a3 += w * bf2f((unsigned short)(v.y >> 16));
    }
    float inv = (end > beg) ? 1.0f / (float)(end - beg) : 0.f;
    a0 *= inv; a1 *= inv; a2 *= inv; a3 *= inv;
    uint2 o;
    o.x = ((unsigned int)f2bf(a1) << 16) | (unsigned int)f2bf(a0);
    o.y = ((unsigned int)f2bf(a3) << 16) | (unsigned int)f2bf(a2);
    out64[(size_t)node * 32 + sub] = o;
}

// ---- fused SAGE linear: out = h @ Wself^T + b + neigh @ Wneigh^T (+relu)
// MFMA 16x16x32 bf16. W0|W1 staged in LDS (row stride 68 uints = 272B,
// 16B-aligned; b128 reads land 2-way bank-aliased = free). Block = 4 waves;
// each wave computes 32 rows x 128 cols (2 row-tiles share every B frag).
// A frag: lane holds A[m=lane&15][k=quad*8+j]; B frag: W[n=lane&15][k=quad*8+j]
// C/D: D[row=quad*4+r][col=lane&15]

#define WROW 68   // uints per W row in LDS (64 data + 4 pad)

__global__ __launch_bounds__(256) void gemm_layer(const unsigned short* __restrict__ A0,
                                                  const unsigned short* __restrict__ A1,
                                                  const unsigned short* __restrict__ W0,
                                                  const unsigned short* __restrict__ W1,
                                                  const unsigned short* __restrict__ bias,
                                                  void* __restrict__ out,
                                                  const unsigned int* __restrict__ emb32,
                                                  int n_rows, int relu, int is_final) {
    __shared__ unsigned int lw[2 * DIM * WROW];   // 69632 B
    int fp32_out = is_final ? block_flag(emb32) : (void(block_flag(emb32)), 0);
    int t = threadIdx.x;

    // stage W0|W1: each W is 2048 uint4-chunks, 16 chunks per 128-ushort row.
    // chunk c -> row = c>>4, uint offset = (c&15)*4.  8 chunks per thread.
#pragma unroll
    for (int mat = 0; mat < 2; ++mat) {
        const uint4* src = (const uint4*)(mat ? W1 : W0);
        unsigned int* dstl = lw + mat * DIM * WROW;
#pragma unroll
        for (int i = 0; i < 8; ++i) {
            int c = i * 256 + t;
            uint4 v = src[c];
            *(uint4*)&dstl[(c >> 4) * WROW + (c & 15) * 4] = v;
        }
    }
    __syncthreads();

    int wave = t >> 6;
    int lane = t & 63;
    int quad = lane >> 4;
    int l16  = lane & 15;
    int m_base = blockIdx.x * 128 + wave * 32;

    floatx4 acc0[8], acc1[8];
#pragma unroll
    for (int c = 0; c < 8; ++c) {
        acc0[c] = (floatx4){0.f, 0.f, 0.f, 0.f};
        acc1[c] = (floatx4){0.f, 0.f, 0.f, 0.f};
    }

    int r0 = min(m_base + l16, n_rows - 1);        // clamp; stores guarded
    int r1 = min(m_base + 16 + l16, n_rows - 1);

#pragma unroll
    for (int mat = 0; mat < 2; ++mat) {
        const unsigned short* A  = mat ? A1 : A0;
        const unsigned int* lwm = lw + mat * DIM * WROW;
        const unsigned short* Ar0 = A + (size_t)r0 * DIM;
        const unsigned short* Ar1 = A + (size_t)r1 * DIM;
#pragma unroll
        for (int ks = 0; ks < 4; ++ks) {
            int k0 = ks * 32 + quad * 8;
            bf16x8 a0 = *(const bf16x8*)(Ar0 + k0);
            bf16x8 a1 = *(const bf16x8*)(Ar1 + k0);
#pragma unroll
            for (int c = 0; c < 8; ++c) {
                bf16x8 b = *(const bf16x8*)&lwm[(c * 16 + l16) * WROW + (k0 >> 1)];
                acc0[c] = __builtin_amdgcn_mfma_f32_16x16x32_bf16(a0, b, acc0[c], 0, 0, 0);
                acc1[c] = __builtin_amdgcn_mfma_f32_16x16x32_bf16(a1, b, acc1[c], 0, 0, 0);
            }
        }
    }

#pragma unroll
    for (int c = 0; c < 8; ++c) {
        int col = c * 16 + l16;
        float bv = bf2f(bias[col]);
#pragma unroll
        for (int r = 0; r < 4; ++r) {
            int row0 = m_base + quad * 4 + r;
            int row1 = row0 + 16;
            if (row0 < n_rows) {
                float v = acc0[c][r] + bv;
                if (relu) v = fmaxf(v, 0.f);
                size_t idx = (size_t)row0 * DIM + col;
                if (fp32_out) ((float*)out)[idx] = v;
                else          ((unsigned short*)out)[idx] = f2bf(v);
            }
            if (row1 < n_rows) {
                float v = acc1[c][r] + bv;
                if (relu) v = fmaxf(v, 0.f);
                size_t idx = (size_t)row1 * DIM + col;
                if (fp32_out) ((float*)out)[idx] = v;
                else          ((unsigned short*)out)[idx] = f2bf(v);
            }
        }
    }
}

// ---- launch ------------------------------------------------------------

extern "C" void kernel_launch(void* const* d_in, const int* in_sizes, int n_in,
                              void* d_out, int out_size, void* d_ws, size_t ws_size,
                              hipStream_t stream) {
    const int* node_ids = (const int*)d_in[0];
    const int* edge_src = (const int*)d_in[1];
    const int* edge_dst = (const int*)d_in[2];
    const void* edge_w  = d_in[3];
    const void* emb     = d_in[4];
    const void* Ws1     = d_in[5];
    const void* Wn1     = d_in[6];
    const void* b1      = d_in[7];
    const void* Ws2     = d_in[8];
    const void* Wn2     = d_in[9];
    const void* b2      = d_in[10];

    const int N = in_sizes[0];
    const int E = in_sizes[1];

    char* w = (char*)d_ws;
    auto alloc = [&](size_t bytes) {
        char* p = w;
        w += (bytes + 255) & ~(size_t)255;
        return p;
    };
    int* partials       = (int*)alloc((size_t)SCAN_BLOCKS * 4);
    int* row_ptr        = (int*)alloc((size_t)(N + 1) * 4);
    int* cnt            = (int*)alloc((size_t)N * CP * 4);   // padded counters/cursors
    const int W = DIM * DIM;
    unsigned short* wcat = (unsigned short*)alloc((size_t)(4 * W + 2 * DIM) * 2);
    unsigned short* Ws1c = wcat;
    unsigned short* Wn1c = wcat + W;
    unsigned short* Ws2c = wcat + 2 * W;
    unsigned short* Wn2c = wcat + 3 * W;
    unsigned short* b1c  = wcat + 4 * W;
    unsigned short* b2c  = wcat + 4 * W + DIM;
    unsigned int* s_edge = (unsigned int*)alloc((size_t)E * 4);
    unsigned short* h0  = (unsigned short*)alloc((size_t)N * DIM * 2);
    unsigned short* h1  = (unsigned short*)alloc((size_t)N * DIM * 2);
    unsigned short* ngh = (unsigned short*)alloc((size_t)N * DIM * 2);

    const unsigned int* emb32 = (const unsigned int*)emb;

    hipMemsetAsync(cnt, 0, (size_t)N * CP * 4, stream);
    hist_kernel<<<(E + 1023) / 1024, 256, 0, stream>>>(edge_dst, cnt, E);
    scan_partial<<<SCAN_BLOCKS, 256, 0, stream>>>(cnt, partials, N);
    scan_final<<<SCAN_BLOCKS, 256, 0, stream>>>(cnt, row_ptr, partials, N);

    const int CN = 4 * W + 2 * DIM;
    const int scat_blocks = (E + 255) / 256;
    const int conv_blocks = (CN + 255) / 256;
    const int gather_total = N * 64;
    const int gather_blocks = (gather_total + 255) / 256;
    scatter_prep_kernel<<<scat_blocks + conv_blocks + gather_blocks, 256, 0, stream>>>(
        edge_src, edge_dst, edge_w, cnt, s_edge, E,
        Ws1, Wn1, Ws2, Wn2, b1, b2, wcat, node_ids, emb,
        (unsigned int*)h0, scat_blocks, conv_blocks, gather_total);

    // Layer 1
    agg_kernel<<<(N + 7) / 8, 256, 0, stream>>>((const uint2*)h0, row_ptr,
                                                s_edge, (uint2*)ngh, N, E);
    gemm_layer<<<(N + 127) / 128, 256, 0, stream>>>(h0, ngh, Ws1c, Wn1c, b1c,
                                                    h1, emb32, N, 1, 0);

    // Layer 2
    agg_kernel<<<(N + 7) / 8, 256, 0, stream>>>((const uint2*)h1, row_ptr,
                                                s_edge, (uint2*)ngh, N, E);
    gemm_layer<<<(N + 127) / 128, 256, 0, stream>>>(h1, ngh, Ws2c, Wn2c, b2c,
                                                    d_out, emb32, N, 0, 1);
}

// Round 10
// 215.211 us; speedup vs baseline: 2.3372x; 1.1418x over previous
//
#include <hip/hip_runtime.h>
#include <stdint.h>

// N=50000 nodes, E=600000 edges, D=128.  Edge records pack src into 16 bits
// -> requires N <= 65536 (true here). Buckets: dst>>8, NB = ceil(N/256) <= 256.
#define DIM 128

typedef __attribute__((ext_vector_type(8))) short bf16x8;
typedef __attribute__((ext_vector_type(4))) float floatx4;

__device__ __forceinline__ float bf2f(unsigned short u) {
    union { unsigned int i; float f; } v; v.i = ((unsigned int)u) << 16; return v.f;
}
__device__ __forceinline__ unsigned short f2bf(float f) {
    union { float f; unsigned int i; } v; v.f = f;
    unsigned int r = (v.i + 0x7FFFu + ((v.i >> 16) & 1u)) >> 16;
    return (unsigned short)r;
}

// Per-block dtype flag: 1 = inputs are fp32, 0 = bf16.
__device__ __forceinline__ int block_flag(const unsigned int* __restrict__ emb32) {
    __shared__ int sf;
    if (threadIdx.x < 64) {
        unsigned int v = emb32[threadIdx.x];
        float f = bf2f((unsigned short)(v & 0xffffu));
        int bad = !(fabsf(f) < 1e4f);   // catches NaN too
        unsigned long long m = __ballot(bad);
        if (threadIdx.x == 0) sf = (__popcll(m) > 16) ? 1 : 0;
    }
    __syncthreads();
    return sf;
}

// ---- bucketed CSR build (no global atomics, XCD-local final stores) ----

// Pass 1: per-(block,bucket) histogram. grid=256.
__global__ __launch_bounds__(256) void bucket_hist(const int* __restrict__ dst,
                                                   int* __restrict__ bcnt, int E, int NB) {
    __shared__ int cnt[256];
    int t = threadIdx.x, j = blockIdx.x;
    cnt[t] = 0;
    __syncthreads();
    int chunk = (E + 255) / 256;
    int beg = j * chunk;
    int end = min(beg + chunk, E);
    for (int e = beg + t; e < end; e += 256) atomicAdd(&cnt[(dst[e] >> 8) & 255], 1);
    __syncthreads();
    if (t < NB) bcnt[j * NB + t] = cnt[t];
}

// Pass 2: per-bucket exclusive scan over blocks. grid=NB, block k = bucket.
__global__ __launch_bounds__(256) void bucket_scan(const int* __restrict__ bcnt,
                                                   int* __restrict__ boff,
                                                   int* __restrict__ btot, int NB) {
    __shared__ int tile[256];
    int t = threadIdx.x, k = blockIdx.x;
    int v = bcnt[t * NB + k];
    tile[t] = v;
    __syncthreads();
    for (int off = 1; off < 256; off <<= 1) {
        int x = (t >= off) ? tile[t - off] : 0;
        __syncthreads();
        tile[t] += x;
        __syncthreads();
    }
    boff[t * NB + k] = tile[t] - v;     // exclusive over blocks < t
    if (t == 255) btot[k] = tile[255];
}

// Pass 3: scatter into bucket-major s_tmp via LDS cursors. grid=256.
__global__ __launch_bounds__(256) void bucket_scatter(
        const int* __restrict__ src, const int* __restrict__ dst,
        const void* __restrict__ w_any, const unsigned int* __restrict__ emb32,
        const int* __restrict__ boff, const int* __restrict__ btot,
        unsigned int* __restrict__ s_tmp, unsigned char* __restrict__ s_tmpb,
        int E, int NB) {
    int flag = block_flag(emb32);
    __shared__ int bs[256];
    __shared__ int cursor[256];
    int t = threadIdx.x, j = blockIdx.x;
    int bv = (t < NB) ? btot[t] : 0;
    bs[t] = bv;
    __syncthreads();
    for (int off = 1; off < 256; off <<= 1) {
        int x = (t >= off) ? bs[t - off] : 0;
        __syncthreads();
        bs[t] += x;
        __syncthreads();
    }
    cursor[t] = (bs[t] - bv) + ((t < NB) ? boff[j * NB + t] : 0);
    __syncthreads();
    int chunk = (E + 255) / 256;
    int beg = j * chunk;
    int end = min(beg + chunk, E);
    for (int e = beg + t; e < end; e += 256) {
        int d = dst[e];
        unsigned short wb = flag ? f2bf(((const float*)w_any)[e])
                                 : ((const unsigned short*)w_any)[e];
        unsigned int rec = ((unsigned int)src[e] & 0xffffu) | ((unsigned int)wb << 16);
        int pos = atomicAdd(&cursor[(d >> 8) & 255], 1);
        s_tmp[pos] = rec;
        s_tmpb[pos] = (unsigned char)(d & 255);
    }
}

// Pass 4: one block per bucket -> row_ptr + dense dst-sorted s_edge.
// The bucket's CSR region is contiguous and written by one block (one XCD).
__global__ __launch_bounds__(256) void bucket_csr(
        const int* __restrict__ btot,
        const unsigned int* __restrict__ s_tmp, const unsigned char* __restrict__ s_tmpb,
        unsigned int* __restrict__ s_edge, int* __restrict__ row_ptr, int N, int NB) {
    __shared__ int bs[256];
    __shared__ int hist[256];
    __shared__ int cur[256];
    int t = threadIdx.x, b = blockIdx.x;
    int bv = (t < NB) ? btot[t] : 0;
    bs[t] = bv;
    __syncthreads();
    for (int off = 1; off < 256; off <<= 1) {
        int x = (t >= off) ? bs[t - off] : 0;
        __syncthreads();
        bs[t] += x;
        __syncthreads();
    }
    int myEnd = bs[b];                 // inclusive prefix (broadcast read)
    int myStart = myEnd - btot[b];
    hist[t] = 0;
    __syncthreads();
    for (int e = myStart + t; e < myEnd; e += 256) atomicAdd(&hist[s_tmpb[e]], 1);
    __syncthreads();
    int hv = hist[t];
    for (int off = 1; off < 256; off <<= 1) {
        int x = (t >= off) ? hist[t - off] : 0;
        __syncthreads();
        hist[t] += x;
        __syncthreads();
    }
    int rowstart = myStart + hist[t] - hv;   // exclusive within bucket
    int node = b * 256 + t;
    if (node < N) row_ptr[node] = rowstart;
    if (b == NB - 1 && t == 0) row_ptr[N] = myEnd;   // == E
    cur[t] = rowstart;
    __syncthreads();
    for (int e = myStart + t; e < myEnd; e += 256) {
        unsigned int rec = s_tmp[e];
        int pos = atomicAdd(&cur[s_tmpb[e]], 1);
        s_edge[pos] = rec;
    }
}

// ---- prep: weight/bias canonicalization + h0 = emb[node_ids] -----------
__global__ __launch_bounds__(256) void prep_kernel(
        const void* __restrict__ s0, const void* __restrict__ s1,
        const void* __restrict__ s2, const void* __restrict__ s3,
        const void* __restrict__ s4, const void* __restrict__ s5,
        unsigned short* __restrict__ wcat,
        const int* __restrict__ ids, const void* __restrict__ emb,
        unsigned int* __restrict__ h032,
        int conv_blocks, int total_gather) {
    int flag = block_flag((const unsigned int*)emb);
    const int W = DIM * DIM;
    int blk = (int)blockIdx.x;
    if (blk < conv_blocks) {
        int i = blk * 256 + threadIdx.x;
        const void* srcp; int off;
        if      (i < W)             { srcp = s0; off = i; }
        else if (i < 2 * W)         { srcp = s1; off = i - W; }
        else if (i < 3 * W)         { srcp = s2; off = i - 2 * W; }
        else if (i < 4 * W)         { srcp = s3; off = i - 3 * W; }
        else if (i < 4 * W + DIM)   { srcp = s4; off = i - 4 * W; }
        else if (i < 4 * W + 2*DIM) { srcp = s5; off = i - 4 * W - DIM; }
        else return;
        wcat[i] = flag ? f2bf(((const float*)srcp)[off])
                       : ((const unsigned short*)srcp)[off];
    } else {
        int t = (blk - conv_blocks) * 256 + threadIdx.x;
        if (t >= total_gather) return;
        int n = t >> 6;           // 64 uints (=128 bf16) per row
        int f = t & 63;
        int id = ids[n];
        unsigned int o;
        if (flag) {
            const float* e = (const float*)emb + (size_t)id * DIM + f * 2;
            o = ((unsigned int)f2bf(e[1]) << 16) | (unsigned int)f2bf(e[0]);
        } else {
            o = ((const unsigned int*)emb)[(size_t)id * 64 + f];
        }
        h032[t] = o;
    }
}

// ---- neighbor mean: TWO nodes per wave (half-wave x uint2), unroll x8 ---

__global__ __launch_bounds__(256) void agg_kernel(const uint2* __restrict__ h64,
                                                  const int* __restrict__ row_ptr,
                                                  const unsigned int* __restrict__ s_edge,
                                                  uint2* __restrict__ out64,
                                                  int N, int E) {
    int lane = threadIdx.x & 63;
    int half = lane >> 5;       // 0 or 1
    int sub  = lane & 31;       // position within the row (uint2 granularity)
    int node = blockIdx.x * 8 + (threadIdx.x >> 6) * 2 + half;
    if (node >= N) return;
    int beg = max(row_ptr[node], 0);
    int end = min(row_ptr[node + 1], E);
    float a0 = 0.f, a1 = 0.f, a2 = 0.f, a3 = 0.f;
    int e = beg;
    for (; e + 8 <= end; e += 8) {
        unsigned int r[8]; int k[8]; float w[8]; uint2 v[8];
#pragma unroll
        for (int i = 0; i < 8; ++i) r[i] = s_edge[e + i];
#pragma unroll
        for (int i = 0; i < 8; ++i) {
            k[i] = min((int)(r[i] & 0xffffu), N - 1);
            w[i] = bf2f((unsigned short)(r[i] >> 16));
        }
#pragma unroll
        for (int i = 0; i < 8; ++i) v[i] = h64[(size_t)k[i] * 32 + sub];
#pragma unroll
        for (int i = 0; i < 8; ++i) {
            a0 += w[i] * bf2f((unsigned short)(v[i].x & 0xffffu));
            a1 += w[i] * bf2f((unsigned short)(v[i].x >> 16));
            a2 += w[i] * bf2f((unsigned short)(v[i].y & 0xffffu));
            a3 += w[i] * bf2f((unsigned short)(v[i].y >> 16));
        }
    }
    for (; e + 4 <= end; e += 4) {
        unsigned int r[4]; int k[4]; float w[4]; uint2 v[4];
#pragma unroll
        for (int i = 0; i < 4; ++i) r[i] = s_edge[e + i];
#pragma unroll
        for (int i = 0; i < 4; ++i) {
            k[i] = min((int)(r[i] & 0xffffu), N - 1);
            w[i] = bf2f((unsigned short)(r[i] >> 16));
        }
#pragma unroll
        for (int i = 0; i < 4; ++i) v[i] = h64[(size_t)k[i] * 32 + sub];
#pragma unroll
        for (int i = 0; i < 4; ++i) {
            a0 += w[i] * bf2f((unsigned short)(v[i].x & 0xffffu));
            a1 += w[i] * bf2f((unsigned short)(v[i].x >> 16));
            a2 += w[i] * bf2f((unsigned short)(v[i].y & 0xffffu));
            a3 += w[i] * bf2f((unsigned short)(v[i].y >> 16));
        }
    }
    for (; e < end; ++e) {
        unsigned int r = s_edge[e];
        int k = min((int)(r & 0xffffu), N - 1);
        float w = bf2f((unsigned short)(r >> 16));
        uint2 v = h64[(size_t)k * 32 + sub];
        a0 += w * bf2f((unsigned short)(v.x & 0xffffu));
        a1 += w * bf2f((unsigned short)(v.x >> 16));
        a2 += w * bf2f((unsigned short)(v.y & 0xffffu));
        a3 += w * bf2f((unsigned short)(v.y >> 16));
    }
    float inv = (end > beg) ? 1.0f / (float)(end - beg) : 0.f;
    a0 *= inv; a1 *= inv; a2 *= inv; a3 *= inv;
    uint2 o;
    o.x = ((unsigned int)f2bf(a1) << 16) | (unsigned int)f2bf(a0);
    o.y = ((unsigned int)f2bf(a3) << 16) | (unsigned int)f2bf(a2);
    out64[(size_t)node * 32 + sub] = o;
}

// ---- fused SAGE linear: out = h @ Wself^T + b + neigh @ Wneigh^T (+relu)
// MFMA 16x16x32 bf16. W0|W1 staged in LDS (row stride 68 uints = 272B).
// Block = 4 waves; each wave computes 32 rows x 128 cols.
// A frag: lane holds A[m=lane&15][k=quad*8+j]; B frag: W[n=lane&15][k=quad*8+j]
// C/D: D[row=quad*4+r][col=lane&15]

#define WROW 68   // uints per W row in LDS (64 data + 4 pad)

__global__ __launch_bounds__(256) void gemm_layer(const unsigned short* __restrict__ A0,
                                                  const unsigned short* __restrict__ A1,
                                                  const unsigned short* __restrict__ W0,
                                                  const unsigned short* __restrict__ W1,
                                                  const unsigned short* __restrict__ bias,
                                                  void* __restrict__ out,
                                                  const unsigned int* __restrict__ emb32,
                                                  int n_rows, int relu, int is_final) {
    __shared__ unsigned int lw[2 * DIM * WROW];   // 69632 B
    int fp32_out = is_final ? block_flag(emb32) : (void(block_flag(emb32)), 0);
    int t = threadIdx.x;

    // stage W0|W1: each W is 2048 uint4-chunks, 16 chunks per 128-ushort row.
    // chunk c -> row = c>>4, uint offset = (c&15)*4.  8 chunks per thread.
#pragma unroll
    for (int mat = 0; mat < 2; ++mat) {
        const uint4* src = (const uint4*)(mat ? W1 : W0);
        unsigned int* dstl = lw + mat * DIM * WROW;
#pragma unroll
        for (int i = 0; i < 8; ++i) {
            int c = i * 256 + t;
            uint4 v = src[c];
            *(uint4*)&dstl[(c >> 4) * WROW + (c & 15) * 4] = v;
        }
    }
    __syncthreads();

    int wave = t >> 6;
    int lane = t & 63;
    int quad = lane >> 4;
    int l16  = lane & 15;
    int m_base = blockIdx.x * 128 + wave * 32;

    floatx4 acc0[8], acc1[8];
#pragma unroll
    for (int c = 0; c < 8; ++c) {
        acc0[c] = (floatx4){0.f, 0.f, 0.f, 0.f};
        acc1[c] = (floatx4){0.f, 0.f, 0.f, 0.f};
    }

    int r0 = min(m_base + l16, n_rows - 1);        // clamp; stores guarded
    int r1 = min(m_base + 16 + l16, n_rows - 1);

#pragma unroll
    for (int mat = 0; mat < 2; ++mat) {
        const unsigned short* A  = mat ? A1 : A0;
        const unsigned int* lwm = lw + mat * DIM * WROW;
        const unsigned short* Ar0 = A + (size_t)r0 * DIM;
        const unsigned short* Ar1 = A + (size_t)r1 * DIM;
#pragma unroll
        for (int ks = 0; ks < 4; ++ks) {
            int k0 = ks * 32 + quad * 8;
            bf16x8 a0 = *(const bf16x8*)(Ar0 + k0);
            bf16x8 a1 = *(const bf16x8*)(Ar1 + k0);
#pragma unroll
            for (int c = 0; c < 8; ++c) {
                bf16x8 b = *(const bf16x8*)&lwm[(c * 16 + l16) * WROW + (k0 >> 1)];
                acc0[c] = __builtin_amdgcn_mfma_f32_16x16x32_bf16(a0, b, acc0[c], 0, 0, 0);
                acc1[c] = __builtin_amdgcn_mfma_f32_16x16x32_bf16(a1, b, acc1[c], 0, 0, 0);
            }
        }
    }

#pragma unroll
    for (int c = 0; c < 8; ++c) {
        int col = c * 16 + l16;
        float bv = bf2f(bias[col]);
#pragma unroll
        for (int r = 0; r < 4; ++r) {
            int row0 = m_base + quad * 4 + r;
            int row1 = row0 + 16;
            if (row0 < n_rows) {
                float v = acc0[c][r] + bv;
                if (relu) v = fmaxf(v, 0.f);
                size_t idx = (size_t)row0 * DIM + col;
                if (fp32_out) ((float*)out)[idx] = v;
                else          ((unsigned short*)out)[idx] = f2bf(v);
            }
            if (row1 < n_rows) {
                float v = acc1[c][r] + bv;
                if (relu) v = fmaxf(v, 0.f);
                size_t idx = (size_t)row1 * DIM + col;
                if (fp32_out) ((float*)out)[idx] = v;
                else          ((unsigned short*)out)[idx] = f2bf(v);
            }
        }
    }
}

// ---- launch ------------------------------------------------------------

extern "C" void kernel_launch(void* const* d_in, const int* in_sizes, int n_in,
                              void* d_out, int out_size, void* d_ws, size_t ws_size,
                              hipStream_t stream) {
    const int* node_ids = (const int*)d_in[0];
    const int* edge_src = (const int*)d_in[1];
    const int* edge_dst = (const int*)d_in[2];
    const void* edge_w  = d_in[3];
    const void* emb     = d_in[4];
    const void* Ws1     = d_in[5];
    const void* Wn1     = d_in[6];
    const void* b1      = d_in[7];
    const void* Ws2     = d_in[8];
    const void* Wn2     = d_in[9];
    const void* b2      = d_in[10];

    const int N = in_sizes[0];
    const int E = in_sizes[1];
    const int NB = (N + 255) >> 8;   // <= 256 since N <= 65536

    char* w = (char*)d_ws;
    auto alloc = [&](size_t bytes) {
        char* p = w;
        w += (bytes + 255) & ~(size_t)255;
        return p;
    };
    int* bcnt           = (int*)alloc((size_t)256 * NB * 4);
    int* boff           = (int*)alloc((size_t)256 * NB * 4);
    int* btot           = (int*)alloc((size_t)256 * 4);
    int* row_ptr        = (int*)alloc((size_t)(N + 1) * 4);
    const int W = DIM * DIM;
    unsigned short* wcat = (unsigned short*)alloc((size_t)(4 * W + 2 * DIM) * 2);
    unsigned short* Ws1c = wcat;
    unsigned short* Wn1c = wcat + W;
    unsigned short* Ws2c = wcat + 2 * W;
    unsigned short* Wn2c = wcat + 3 * W;
    unsigned short* b1c  = wcat + 4 * W;
    unsigned short* b2c  = wcat + 4 * W + DIM;
    unsigned int* s_tmp  = (unsigned int*)alloc((size_t)E * 4);
    unsigned char* s_tmpb = (unsigned char*)alloc((size_t)E);
    unsigned int* s_edge = (unsigned int*)alloc((size_t)E * 4);
    unsigned short* h0  = (unsigned short*)alloc((size_t)N * DIM * 2);
    unsigned short* h1  = (unsigned short*)alloc((size_t)N * DIM * 2);
    unsigned short* ngh = (unsigned short*)alloc((size_t)N * DIM * 2);

    const unsigned int* emb32 = (const unsigned int*)emb;

    // CSR build (bucketed counting sort, no global atomics, no memset)
    bucket_hist<<<256, 256, 0, stream>>>(edge_dst, bcnt, E, NB);
    bucket_scan<<<NB, 256, 0, stream>>>(bcnt, boff, btot, NB);
    bucket_scatter<<<256, 256, 0, stream>>>(edge_src, edge_dst, edge_w, emb32,
                                            boff, btot, s_tmp, s_tmpb, E, NB);
    bucket_csr<<<NB, 256, 0, stream>>>(btot, s_tmp, s_tmpb, s_edge, row_ptr, N, NB);

    const int CN = 4 * W + 2 * DIM;
    const int conv_blocks = (CN + 255) / 256;
    const int gather_total = N * 64;
    const int gather_blocks = (gather_total + 255) / 256;
    prep_kernel<<<conv_blocks + gather_blocks, 256, 0, stream>>>(
        Ws1, Wn1, Ws2, Wn2, b1, b2, wcat, node_ids, emb,
        (unsigned int*)h0, conv_blocks, gather_total);

    // Layer 1
    agg_kernel<<<(N + 7) / 8, 256, 0, stream>>>((const uint2*)h0, row_ptr,
                                                s_edge, (uint2*)ngh, N, E);
    gemm_layer<<<(N + 127) / 128, 256, 0, stream>>>(h0, ngh, Ws1c, Wn1c, b1c,
                                                    h1, emb32, N, 1, 0);

    // Layer 2
    agg_kernel<<<(N + 7) / 8, 256, 0, stream>>>((const uint2*)h1, row_ptr,
                                                s_edge, (uint2*)ngh, N, E);
    gemm_layer<<<(N + 127) / 128, 256, 0, stream>>>(h1, ngh, Ws2c, Wn2c, b2c,
                                                    d_out, emb32, N, 0, 1);
}

// Round 11
// 211.511 us; speedup vs baseline: 2.3781x; 1.0175x over previous
//
#include <hip/hip_runtime.h>
#include <stdint.h>

// N=50000 nodes, E=600000 edges, D=128.  Edge records pack src into 16 bits
// -> requires N <= 65536 (true here). Buckets: dst>>8, NB = ceil(N/256) <= 256.
#define DIM 128

typedef __attribute__((ext_vector_type(8))) short bf16x8;
typedef __attribute__((ext_vector_type(4))) float floatx4;

__device__ __forceinline__ float bf2f(unsigned short u) {
    union { unsigned int i; float f; } v; v.i = ((unsigned int)u) << 16; return v.f;
}
__device__ __forceinline__ unsigned short f2bf(float f) {
    union { float f; unsigned int i; } v; v.f = f;
    unsigned int r = (v.i + 0x7FFFu + ((v.i >> 16) & 1u)) >> 16;
    return (unsigned short)r;
}
__device__ __forceinline__ unsigned int pack2(float lo, float hi) {
    return ((unsigned int)f2bf(hi) << 16) | (unsigned int)f2bf(lo);
}

// Per-block dtype flag: 1 = inputs are fp32, 0 = bf16.
__device__ __forceinline__ int block_flag(const unsigned int* __restrict__ emb32) {
    __shared__ int sf;
    if (threadIdx.x < 64) {
        unsigned int v = emb32[threadIdx.x];
        float f = bf2f((unsigned short)(v & 0xffffu));
        int bad = !(fabsf(f) < 1e4f);   // catches NaN too
        unsigned long long m = __ballot(bad);
        if (threadIdx.x == 0) sf = (__popcll(m) > 16) ? 1 : 0;
    }
    __syncthreads();
    return sf;
}

// ---- Pass 1 + prep (merged): histogram ∥ weight-convert ∥ h0-gather ----
// blockIdx < 256                 : per-(block,bucket) histogram
// blockIdx < 256+conv_blocks     : convert Ws1|Wn1|Ws2|Wn2|b1|b2 -> wcat
// else                           : gather h0 = emb[node_ids] (bf16)
__global__ __launch_bounds__(256) void hist_prep_kernel(
        const int* __restrict__ dst, int* __restrict__ bcnt, int E, int NB,
        const void* __restrict__ s0, const void* __restrict__ s1,
        const void* __restrict__ s2, const void* __restrict__ s3,
        const void* __restrict__ s4, const void* __restrict__ s5,
        unsigned short* __restrict__ wcat,
        const int* __restrict__ ids, const void* __restrict__ emb,
        unsigned int* __restrict__ h032,
        int conv_blocks, int total_gather) {
    const int W = DIM * DIM;
    int blk = (int)blockIdx.x;
    int t = threadIdx.x;
    if (blk < 256) {
        __shared__ int cnt[256];
        cnt[t] = 0;
        __syncthreads();
        int chunk = (E + 255) / 256;
        int beg = blk * chunk;
        int end = min(beg + chunk, E);
        for (int e = beg + t; e < end; e += 256) atomicAdd(&cnt[(dst[e] >> 8) & 255], 1);
        __syncthreads();
        if (t < NB) bcnt[blk * NB + t] = cnt[t];
    } else if (blk < 256 + conv_blocks) {
        int flag = block_flag((const unsigned int*)emb);
        int i = (blk - 256) * 256 + t;
        const void* srcp; int off;
        if      (i < W)             { srcp = s0; off = i; }
        else if (i < 2 * W)         { srcp = s1; off = i - W; }
        else if (i < 3 * W)         { srcp = s2; off = i - 2 * W; }
        else if (i < 4 * W)         { srcp = s3; off = i - 3 * W; }
        else if (i < 4 * W + DIM)   { srcp = s4; off = i - 4 * W; }
        else if (i < 4 * W + 2*DIM) { srcp = s5; off = i - 4 * W - DIM; }
        else return;
        wcat[i] = flag ? f2bf(((const float*)srcp)[off])
                       : ((const unsigned short*)srcp)[off];
    } else {
        int flag = block_flag((const unsigned int*)emb);
        int g = (blk - 256 - conv_blocks) * 256 + t;
        if (g >= total_gather) return;
        int n = g >> 6;           // 64 uints (=128 bf16) per row
        int f = g & 63;
        int id = ids[n];
        unsigned int o;
        if (flag) {
            const float* e = (const float*)emb + (size_t)id * DIM + f * 2;
            o = (pack2(e[0], e[1]));
        } else {
            o = ((const unsigned int*)emb)[(size_t)id * 64 + f];
        }
        h032[g] = o;
    }
}

// Pass 2: per-bucket exclusive scan over blocks. grid=NB, block k = bucket.
__global__ __launch_bounds__(256) void bucket_scan(const int* __restrict__ bcnt,
                                                   int* __restrict__ boff,
                                                   int* __restrict__ btot, int NB) {
    __shared__ int tile[256];
    int t = threadIdx.x, k = blockIdx.x;
    int v = bcnt[t * NB + k];
    tile[t] = v;
    __syncthreads();
    for (int off = 1; off < 256; off <<= 1) {
        int x = (t >= off) ? tile[t - off] : 0;
        __syncthreads();
        tile[t] += x;
        __syncthreads();
    }
    boff[t * NB + k] = tile[t] - v;     // exclusive over blocks < t
    if (t == 255) btot[k] = tile[255];
}

// Pass 3: scatter into bucket-major s_tmp via LDS cursors. grid=256.
__global__ __launch_bounds__(256) void bucket_scatter(
        const int* __restrict__ src, const int* __restrict__ dst,
        const void* __restrict__ w_any, const unsigned int* __restrict__ emb32,
        const int* __restrict__ boff, const int* __restrict__ btot,
        unsigned int* __restrict__ s_tmp, unsigned char* __restrict__ s_tmpb,
        int E, int NB) {
    int flag = block_flag(emb32);
    __shared__ int bs[256];
    __shared__ int cursor[256];
    int t = threadIdx.x, j = blockIdx.x;
    int bv = (t < NB) ? btot[t] : 0;
    bs[t] = bv;
    __syncthreads();
    for (int off = 1; off < 256; off <<= 1) {
        int x = (t >= off) ? bs[t - off] : 0;
        __syncthreads();
        bs[t] += x;
        __syncthreads();
    }
    cursor[t] = (bs[t] - bv) + ((t < NB) ? boff[j * NB + t] : 0);
    __syncthreads();
    int chunk = (E + 255) / 256;
    int beg = j * chunk;
    int end = min(beg + chunk, E);
    for (int e = beg + t; e < end; e += 256) {
        int d = dst[e];
        unsigned short wb = flag ? f2bf(((const float*)w_any)[e])
                                 : ((const unsigned short*)w_any)[e];
        unsigned int rec = ((unsigned int)src[e] & 0xffffu) | ((unsigned int)wb << 16);
        int pos = atomicAdd(&cursor[(d >> 8) & 255], 1);
        s_tmp[pos] = rec;
        s_tmpb[pos] = (unsigned char)(d & 255);
    }
}

// Pass 4: one block per bucket -> row_ptr + dense dst-sorted s_edge.
__global__ __launch_bounds__(256) void bucket_csr(
        const int* __restrict__ btot,
        const unsigned int* __restrict__ s_tmp, const unsigned char* __restrict__ s_tmpb,
        unsigned int* __restrict__ s_edge, int* __restrict__ row_ptr, int N, int NB) {
    __shared__ int bs[256];
    __shared__ int hist[256];
    __shared__ int cur[256];
    int t = threadIdx.x, b = blockIdx.x;
    int bv = (t < NB) ? btot[t] : 0;
    bs[t] = bv;
    __syncthreads();
    for (int off = 1; off < 256; off <<= 1) {
        int x = (t >= off) ? bs[t - off] : 0;
        __syncthreads();
        bs[t] += x;
        __syncthreads();
    }
    int myEnd = bs[b];                 // inclusive prefix (broadcast read)
    int myStart = myEnd - btot[b];
    hist[t] = 0;
    __syncthreads();
    for (int e = myStart + t; e < myEnd; e += 256) atomicAdd(&hist[s_tmpb[e]], 1);
    __syncthreads();
    int hv = hist[t];
    for (int off = 1; off < 256; off <<= 1) {
        int x = (t >= off) ? hist[t - off] : 0;
        __syncthreads();
        hist[t] += x;
        __syncthreads();
    }
    int rowstart = myStart + hist[t] - hv;   // exclusive within bucket
    int node = b * 256 + t;
    if (node < N) row_ptr[node] = rowstart;
    if (b == NB - 1 && t == 0) row_ptr[N] = myEnd;   // == E
    cur[t] = rowstart;
    __syncthreads();
    for (int e = myStart + t; e < myEnd; e += 256) {
        unsigned int rec = s_tmp[e];
        int pos = atomicAdd(&cur[s_tmpb[e]], 1);
        s_edge[pos] = rec;
    }
}

// ---- neighbor mean: FOUR nodes per wave (quarter-wave x uint4) ----------
// One vmem instruction gathers 4 rows (16 lanes x 16B each) -> 2x bytes in
// flight per wave vs the uint2/half-wave version, half the VALU per byte.

__global__ __launch_bounds__(256) void agg_kernel(const uint4* __restrict__ h128,
                                                  const int* __restrict__ row_ptr,
                                                  const unsigned int* __restrict__ s_edge,
                                                  uint4* __restrict__ out128,
                                                  int N, int E) {
    int lane = threadIdx.x & 63;
    int q    = lane >> 4;       // subgroup 0..3 -> node
    int sub  = lane & 15;       // uint4 index within the 256B row
    int node = blockIdx.x * 16 + (threadIdx.x >> 6) * 4 + q;
    if (node >= N) return;
    int beg = max(row_ptr[node], 0);
    int end = min(row_ptr[node + 1], E);
    float a0 = 0.f, a1 = 0.f, a2 = 0.f, a3 = 0.f;
    float a4 = 0.f, a5 = 0.f, a6 = 0.f, a7 = 0.f;
    int e = beg;
    for (; e + 8 <= end; e += 8) {
        unsigned int r[8]; int k[8]; float w[8]; uint4 v[8];
#pragma unroll
        for (int i = 0; i < 8; ++i) r[i] = s_edge[e + i];
#pragma unroll
        for (int i = 0; i < 8; ++i) {
            k[i] = min((int)(r[i] & 0xffffu), N - 1);
            w[i] = bf2f((unsigned short)(r[i] >> 16));
        }
#pragma unroll
        for (int i = 0; i < 8; ++i) v[i] = h128[(size_t)k[i] * 16 + sub];
#pragma unroll
        for (int i = 0; i < 8; ++i) {
            a0 += w[i] * bf2f((unsigned short)(v[i].x & 0xffffu));
            a1 += w[i] * bf2f((unsigned short)(v[i].x >> 16));
            a2 += w[i] * bf2f((unsigned short)(v[i].y & 0xffffu));
            a3 += w[i] * bf2f((unsigned short)(v[i].y >> 16));
            a4 += w[i] * bf2f((unsigned short)(v[i].z & 0xffffu));
            a5 += w[i] * bf2f((unsigned short)(v[i].z >> 16));
            a6 += w[i] * bf2f((unsigned short)(v[i].w & 0xffffu));
            a7 += w[i] * bf2f((unsigned short)(v[i].w >> 16));
        }
    }
    for (; e + 4 <= end; e += 4) {
        unsigned int r[4]; int k[4]; float w[4]; uint4 v[4];
#pragma unroll
        for (int i = 0; i < 4; ++i) r[i] = s_edge[e + i];
#pragma unroll
        for (int i = 0; i < 4; ++i) {
            k[i] = min((int)(r[i] & 0xffffu), N - 1);
            w[i] = bf2f((unsigned short)(r[i] >> 16));
        }
#pragma unroll
        for (int i = 0; i < 4; ++i) v[i] = h128[(size_t)k[i] * 16 + sub];
#pragma unroll
        for (int i = 0; i < 4; ++i) {
            a0 += w[i] * bf2f((unsigned short)(v[i].x & 0xffffu));
            a1 += w[i] * bf2f((unsigned short)(v[i].x >> 16));
            a2 += w[i] * bf2f((unsigned short)(v[i].y & 0xffffu));
            a3 += w[i] * bf2f((unsigned short)(v[i].y >> 16));
            a4 += w[i] * bf2f((unsigned short)(v[i].z & 0xffffu));
            a5 += w[i] * bf2f((unsigned short)(v[i].z >> 16));
            a6 += w[i] * bf2f((unsigned short)(v[i].w & 0xffffu));
            a7 += w[i] * bf2f((unsigned short)(v[i].w >> 16));
        }
    }
    for (; e < end; ++e) {
        unsigned int r = s_edge[e];
        int k = min((int)(r & 0xffffu), N - 1);
        float w = bf2f((unsigned short)(r >> 16));
        uint4 v = h128[(size_t)k * 16 + sub];
        a0 += w * bf2f((unsigned short)(v.x & 0xffffu));
        a1 += w * bf2f((unsigned short)(v.x >> 16));
        a2 += w * bf2f((unsigned short)(v.y & 0xffffu));
        a3 += w * bf2f((unsigned short)(v.y >> 16));
        a4 += w * bf2f((unsigned short)(v.z & 0xffffu));
        a5 += w * bf2f((unsigned short)(v.z >> 16));
        a6 += w * bf2f((unsigned short)(v.w & 0xffffu));
        a7 += w * bf2f((unsigned short)(v.w >> 16));
    }
    float inv = (end > beg) ? 1.0f / (float)(end - beg) : 0.f;
    uint4 o;
    o.x = pack2(a0 * inv, a1 * inv);
    o.y = pack2(a2 * inv, a3 * inv);
    o.z = pack2(a4 * inv, a5 * inv);
    o.w = pack2(a6 * inv, a7 * inv);
    out128[(size_t)node * 16 + sub] = o;
}

// ---- fused SAGE linear: out = h @ Wself^T + b + neigh @ Wneigh^T (+relu)
// MFMA 16x16x32 bf16. W0|W1 staged in LDS (row stride 68 uints = 272B).
// Block = 4 waves; each wave computes 32 rows x 128 cols.
// A frag: lane holds A[m=lane&15][k=quad*8+j]; B frag: W[n=lane&15][k=quad*8+j]
// C/D: D[row=quad*4+r][col=lane&15]

#define WROW 68   // uints per W row in LDS (64 data + 4 pad)

__global__ __launch_bounds__(256) void gemm_layer(const unsigned short* __restrict__ A0,
                                                  const unsigned short* __restrict__ A1,
                                                  const unsigned short* __restrict__ W0,
                                                  const unsigned short* __restrict__ W1,
                                                  const unsigned short* __restrict__ bias,
                                                  void* __restrict__ out,
                                                  const unsigned int* __restrict__ emb32,
                                                  int n_rows, int relu, int is_final) {
    __shared__ unsigned int lw[2 * DIM * WROW];   // 69632 B
    int fp32_out = is_final ? block_flag(emb32) : (void(block_flag(emb32)), 0);
    int t = threadIdx.x;

    // stage W0|W1: each W is 2048 uint4-chunks, 16 chunks per 128-ushort row.
    // chunk c -> row = c>>4, uint offset = (c&15)*4.  8 chunks per thread.
#pragma unroll
    for (int mat = 0; mat < 2; ++mat) {
        const uint4* src = (const uint4*)(mat ? W1 : W0);
        unsigned int* dstl = lw + mat * DIM * WROW;
#pragma unroll
        for (int i = 0; i < 8; ++i) {
            int c = i * 256 + t;
            uint4 v = src[c];
            *(uint4*)&dstl[(c >> 4) * WROW + (c & 15) * 4] = v;
        }
    }
    __syncthreads();

    int wave = t >> 6;
    int lane = t & 63;
    int quad = lane >> 4;
    int l16  = lane & 15;
    int m_base = blockIdx.x * 128 + wave * 32;

    floatx4 acc0[8], acc1[8];
#pragma unroll
    for (int c = 0; c < 8; ++c) {
        acc0[c] = (floatx4){0.f, 0.f, 0.f, 0.f};
        acc1[c] = (floatx4){0.f, 0.f, 0.f, 0.f};
    }

    int r0 = min(m_base + l16, n_rows - 1);        // clamp; stores guarded
    int r1 = min(m_base + 16 + l16, n_rows - 1);

#pragma unroll
    for (int mat = 0; mat < 2; ++mat) {
        const unsigned short* A  = mat ? A1 : A0;
        const unsigned int* lwm = lw + mat * DIM * WROW;
        const unsigned short* Ar0 = A + (size_t)r0 * DIM;
        const unsigned short* Ar1 = A + (size_t)r1 * DIM;
#pragma unroll
        for (int ks = 0; ks < 4; ++ks) {
            int k0 = ks * 32 + quad * 8;
            bf16x8 a0 = *(const bf16x8*)(Ar0 + k0);
            bf16x8 a1 = *(const bf16x8*)(Ar1 + k0);
#pragma unroll
            for (int c = 0; c < 8; ++c) {
                bf16x8 b = *(const bf16x8*)&lwm[(c * 16 + l16) * WROW + (k0 >> 1)];
                acc0[c] = __builtin_amdgcn_mfma_f32_16x16x32_bf16(a0, b, acc0[c], 0, 0, 0);
                acc1[c] = __builtin_amdgcn_mfma_f32_16x16x32_bf16(a1, b, acc1[c], 0, 0, 0);
            }
        }
    }

#pragma unroll
    for (int c = 0; c < 8; ++c) {
        int col = c * 16 + l16;
        float bv = bf2f(bias[col]);
#pragma unroll
        for (int r = 0; r < 4; ++r) {
            int row0 = m_base + quad * 4 + r;
            int row1 = row0 + 16;
            if (row0 < n_rows) {
                float v = acc0[c][r] + bv;
                if (relu) v = fmaxf(v, 0.f);
                size_t idx = (size_t)row0 * DIM + col;
                if (fp32_out) ((float*)out)[idx] = v;
                else          ((unsigned short*)out)[idx] = f2bf(v);
            }
            if (row1 < n_rows) {
                float v = acc1[c][r] + bv;
                if (relu) v = fmaxf(v, 0.f);
                size_t idx = (size_t)row1 * DIM + col;
                if (fp32_out) ((float*)out)[idx] = v;
                else          ((unsigned short*)out)[idx] = f2bf(v);
            }
        }
    }
}

// ---- launch ------------------------------------------------------------

extern "C" void kernel_launch(void* const* d_in, const int* in_sizes, int n_in,
                              void* d_out, int out_size, void* d_ws, size_t ws_size,
                              hipStream_t stream) {
    const int* node_ids = (const int*)d_in[0];
    const int* edge_src = (const int*)d_in[1];
    const int* edge_dst = (const int*)d_in[2];
    const void* edge_w  = d_in[3];
    const void* emb     = d_in[4];
    const void* Ws1     = d_in[5];
    const void* Wn1     = d_in[6];
    const void* b1      = d_in[7];
    const void* Ws2     = d_in[8];
    const void* Wn2     = d_in[9];
    const void* b2      = d_in[10];

    const int N = in_sizes[0];
    const int E = in_sizes[1];
    const int NB = (N + 255) >> 8;   // <= 256 since N <= 65536

    char* w = (char*)d_ws;
    auto alloc = [&](size_t bytes) {
        char* p = w;
        w += (bytes + 255) & ~(size_t)255;
        return p;
    };
    int* bcnt           = (int*)alloc((size_t)256 * NB * 4);
    int* boff           = (int*)alloc((size_t)256 * NB * 4);
    int* btot           = (int*)alloc((size_t)256 * 4);
    int* row_ptr        = (int*)alloc((size_t)(N + 1) * 4);
    const int W = DIM * DIM;
    unsigned short* wcat = (unsigned short*)alloc((size_t)(4 * W + 2 * DIM) * 2);
    unsigned short* Ws1c = wcat;
    unsigned short* Wn1c = wcat + W;
    unsigned short* Ws2c = wcat + 2 * W;
    unsigned short* Wn2c = wcat + 3 * W;
    unsigned short* b1c  = wcat + 4 * W;
    unsigned short* b2c  = wcat + 4 * W + DIM;
    unsigned int* s_tmp  = (unsigned int*)alloc((size_t)E * 4);
    unsigned char* s_tmpb = (unsigned char*)alloc((size_t)E);
    unsigned int* s_edge = (unsigned int*)alloc((size_t)E * 4);
    unsigned short* h0  = (unsigned short*)alloc((size_t)N * DIM * 2);
    unsigned short* h1  = (unsigned short*)alloc((size_t)N * DIM * 2);
    unsigned short* ngh = (unsigned short*)alloc((size_t)N * DIM * 2);

    const unsigned int* emb32 = (const unsigned int*)emb;

    const int CN = 4 * W + 2 * DIM;
    const int conv_blocks = (CN + 255) / 256;
    const int gather_total = N * 64;
    const int gather_blocks = (gather_total + 255) / 256;

    // hist ∥ prep, then scan -> scatter -> csr
    hist_prep_kernel<<<256 + conv_blocks + gather_blocks, 256, 0, stream>>>(
        edge_dst, bcnt, E, NB,
        Ws1, Wn1, Ws2, Wn2, b1, b2, wcat, node_ids, emb,
        (unsigned int*)h0, conv_blocks, gather_total);
    bucket_scan<<<NB, 256, 0, stream>>>(bcnt, boff, btot, NB);
    bucket_scatter<<<256, 256, 0, stream>>>(edge_src, edge_dst, edge_w, emb32,
                                            boff, btot, s_tmp, s_tmpb, E, NB);
    bucket_csr<<<NB, 256, 0, stream>>>(btot, s_tmp, s_tmpb, s_edge, row_ptr, N, NB);

    // Layer 1
    agg_kernel<<<(N + 15) / 16, 256, 0, stream>>>((const uint4*)h0, row_ptr,
                                                  s_edge, (uint4*)ngh, N, E);
    gemm_layer<<<(N + 127) / 128, 256, 0, stream>>>(h0, ngh, Ws1c, Wn1c, b1c,
                                                    h1, emb32, N, 1, 0);

    // Layer 2
    agg_kernel<<<(N + 15) / 16, 256, 0, stream>>>((const uint4*)h1, row_ptr,
                                                  s_edge, (uint4*)ngh, N, E);
    gemm_layer<<<(N + 127) / 128, 256, 0, stream>>>(h1, ngh, Ws2c, Wn2c, b2c,
                                                    d_out, emb32, N, 0, 1);
}

// Round 12
// 208.470 us; speedup vs baseline: 2.4128x; 1.0146x over previous
//
#include <hip/hip_runtime.h>
#include <stdint.h>

// N=50000 nodes, E=600000 edges, D=128.  Edge records pack src into 16 bits
// -> requires N <= 65536 (true here). Buckets: dst>>8, NB = ceil(N/256) <= 256.
#define DIM 128

typedef __attribute__((ext_vector_type(8))) short bf16x8;
typedef __attribute__((ext_vector_type(4))) float floatx4;

__device__ __forceinline__ float bf2f(unsigned short u) {
    union { unsigned int i; float f; } v; v.i = ((unsigned int)u) << 16; return v.f;
}
__device__ __forceinline__ unsigned short f2bf(float f) {
    union { float f; unsigned int i; } v; v.f = f;
    unsigned int r = (v.i + 0x7FFFu + ((v.i >> 16) & 1u)) >> 16;
    return (unsigned short)r;
}
__device__ __forceinline__ unsigned int pack2(float lo, float hi) {
    return ((unsigned int)f2bf(hi) << 16) | (unsigned int)f2bf(lo);
}

// Per-block dtype flag: 1 = inputs are fp32, 0 = bf16.
__device__ __forceinline__ int block_flag(const unsigned int* __restrict__ emb32) {
    __shared__ int sf;
    if (threadIdx.x < 64) {
        unsigned int v = emb32[threadIdx.x];
        float f = bf2f((unsigned short)(v & 0xffffu));
        int bad = !(fabsf(f) < 1e4f);   // catches NaN too
        unsigned long long m = __ballot(bad);
        if (threadIdx.x == 0) sf = (__popcll(m) > 16) ? 1 : 0;
    }
    __syncthreads();
    return sf;
}

// ---- Pass 1 + prep (merged): histogram ∥ weight-convert ∥ h0-gather ----
// h0-gather is uint4-wide: one 16B chunk per thread.
__global__ __launch_bounds__(256) void hist_prep_kernel(
        const int* __restrict__ dst, int* __restrict__ bcnt, int E, int NB,
        const void* __restrict__ s0, const void* __restrict__ s1,
        const void* __restrict__ s2, const void* __restrict__ s3,
        const void* __restrict__ s4, const void* __restrict__ s5,
        unsigned short* __restrict__ wcat,
        const int* __restrict__ ids, const void* __restrict__ emb,
        uint4* __restrict__ h0v,
        int conv_blocks, int total_gather4) {
    const int W = DIM * DIM;
    int blk = (int)blockIdx.x;
    int t = threadIdx.x;
    if (blk < 256) {
        __shared__ int cnt[256];
        cnt[t] = 0;
        __syncthreads();
        int chunk = (E + 255) / 256;
        int beg = blk * chunk;
        int end = min(beg + chunk, E);
        for (int e = beg + t; e < end; e += 256) atomicAdd(&cnt[(dst[e] >> 8) & 255], 1);
        __syncthreads();
        if (t < NB) bcnt[blk * NB + t] = cnt[t];
    } else if (blk < 256 + conv_blocks) {
        int flag = block_flag((const unsigned int*)emb);
        int i = (blk - 256) * 256 + t;
        const void* srcp; int off;
        if      (i < W)             { srcp = s0; off = i; }
        else if (i < 2 * W)         { srcp = s1; off = i - W; }
        else if (i < 3 * W)         { srcp = s2; off = i - 2 * W; }
        else if (i < 4 * W)         { srcp = s3; off = i - 3 * W; }
        else if (i < 4 * W + DIM)   { srcp = s4; off = i - 4 * W; }
        else if (i < 4 * W + 2*DIM) { srcp = s5; off = i - 4 * W - DIM; }
        else return;
        wcat[i] = flag ? f2bf(((const float*)srcp)[off])
                       : ((const unsigned short*)srcp)[off];
    } else {
        int flag = block_flag((const unsigned int*)emb);
        int g = (blk - 256 - conv_blocks) * 256 + t;
        if (g >= total_gather4) return;
        int n = g >> 4;           // 16 uint4 (=128 bf16) per row
        int f = g & 15;
        int id = ids[n];
        uint4 o;
        if (flag) {
            const float* e = (const float*)emb + (size_t)id * DIM + f * 8;
            o.x = pack2(e[0], e[1]);
            o.y = pack2(e[2], e[3]);
            o.z = pack2(e[4], e[5]);
            o.w = pack2(e[6], e[7]);
        } else {
            o = ((const uint4*)emb)[(size_t)id * 16 + f];
        }
        h0v[g] = o;
    }
}

// Pass 2: per-bucket exclusive scan over blocks. grid=NB, block k = bucket.
__global__ __launch_bounds__(256) void bucket_scan(const int* __restrict__ bcnt,
                                                   int* __restrict__ boff,
                                                   int* __restrict__ btot, int NB) {
    __shared__ int tile[256];
    int t = threadIdx.x, k = blockIdx.x;
    int v = bcnt[t * NB + k];
    tile[t] = v;
    __syncthreads();
    for (int off = 1; off < 256; off <<= 1) {
        int x = (t >= off) ? tile[t - off] : 0;
        __syncthreads();
        tile[t] += x;
        __syncthreads();
    }
    boff[t * NB + k] = tile[t] - v;     // exclusive over blocks < t
    if (t == 255) btot[k] = tile[255];
}

// Pass 3: scatter into bucket-major s_tmp via LDS cursors. grid=256.
__global__ __launch_bounds__(256) void bucket_scatter(
        const int* __restrict__ src, const int* __restrict__ dst,
        const void* __restrict__ w_any, const unsigned int* __restrict__ emb32,
        const int* __restrict__ boff, const int* __restrict__ btot,
        unsigned int* __restrict__ s_tmp, unsigned char* __restrict__ s_tmpb,
        int E, int NB) {
    int flag = block_flag(emb32);
    __shared__ int bs[256];
    __shared__ int cursor[256];
    int t = threadIdx.x, j = blockIdx.x;
    int bv = (t < NB) ? btot[t] : 0;
    bs[t] = bv;
    __syncthreads();
    for (int off = 1; off < 256; off <<= 1) {
        int x = (t >= off) ? bs[t - off] : 0;
        __syncthreads();
        bs[t] += x;
        __syncthreads();
    }
    cursor[t] = (bs[t] - bv) + ((t < NB) ? boff[j * NB + t] : 0);
    __syncthreads();
    int chunk = (E + 255) / 256;
    int beg = j * chunk;
    int end = min(beg + chunk, E);
    for (int e = beg + t; e < end; e += 256) {
        int d = dst[e];
        unsigned short wb = flag ? f2bf(((const float*)w_any)[e])
                                 : ((const unsigned short*)w_any)[e];
        unsigned int rec = ((unsigned int)src[e] & 0xffffu) | ((unsigned int)wb << 16);
        int pos = atomicAdd(&cursor[(d >> 8) & 255], 1);
        s_tmp[pos] = rec;
        s_tmpb[pos] = (unsigned char)(d & 255);
    }
}

// Pass 4: one block per bucket -> row_ptr + dense dst-sorted s_edge.
__global__ __launch_bounds__(256) void bucket_csr(
        const int* __restrict__ btot,
        const unsigned int* __restrict__ s_tmp, const unsigned char* __restrict__ s_tmpb,
        unsigned int* __restrict__ s_edge, int* __restrict__ row_ptr, int N, int NB) {
    __shared__ int bs[256];
    __shared__ int hist[256];
    __shared__ int cur[256];
    int t = threadIdx.x, b = blockIdx.x;
    int bv = (t < NB) ? btot[t] : 0;
    bs[t] = bv;
    __syncthreads();
    for (int off = 1; off < 256; off <<= 1) {
        int x = (t >= off) ? bs[t - off] : 0;
        __syncthreads();
        bs[t] += x;
        __syncthreads();
    }
    int myEnd = bs[b];                 // inclusive prefix (broadcast read)
    int myStart = myEnd - btot[b];
    hist[t] = 0;
    __syncthreads();
    for (int e = myStart + t; e < myEnd; e += 256) atomicAdd(&hist[s_tmpb[e]], 1);
    __syncthreads();
    int hv = hist[t];
    for (int off = 1; off < 256; off <<= 1) {
        int x = (t >= off) ? hist[t - off] : 0;
        __syncthreads();
        hist[t] += x;
        __syncthreads();
    }
    int rowstart = myStart + hist[t] - hv;   // exclusive within bucket
    int node = b * 256 + t;
    if (node < N) row_ptr[node] = rowstart;
    if (b == NB - 1 && t == 0) row_ptr[N] = myEnd;   // == E
    cur[t] = rowstart;
    __syncthreads();
    for (int e = myStart + t; e < myEnd; e += 256) {
        unsigned int rec = s_tmp[e];
        int pos = atomicAdd(&cur[s_tmpb[e]], 1);
        s_edge[pos] = rec;
    }
}

// ---- neighbor mean: FOUR nodes per wave (quarter-wave x uint4) ----------
// Edge records for a node are contiguous: load them 4-at-a-time with uint4
// (align-peel first) -> 2 record loads + 8 row gathers per 8-edge iter
// instead of 8 + 8.

#define AGG_EDGE(RV)                                                      \
    do {                                                                  \
        unsigned int _r = (RV);                                           \
        int _k = (int)(_r & 0xffffu);                                     \
        float _w = bf2f((unsigned short)(_r >> 16));                      \
        uint4 _v = h128[(size_t)_k * 16 + sub];                           \
        a0 += _w * bf2f((unsigned short)(_v.x & 0xffffu));                \
        a1 += _w * bf2f((unsigned short)(_v.x >> 16));                    \
        a2 += _w * bf2f((unsigned short)(_v.y & 0xffffu));                \
        a3 += _w * bf2f((unsigned short)(_v.y >> 16));                    \
        a4 += _w * bf2f((unsigned short)(_v.z & 0xffffu));                \
        a5 += _w * bf2f((unsigned short)(_v.z >> 16));                    \
        a6 += _w * bf2f((unsigned short)(_v.w & 0xffffu));                \
        a7 += _w * bf2f((unsigned short)(_v.w >> 16));                    \
    } while (0)

__global__ __launch_bounds__(256) void agg_kernel(const uint4* __restrict__ h128,
                                                  const int* __restrict__ row_ptr,
                                                  const unsigned int* __restrict__ s_edge,
                                                  uint4* __restrict__ out128,
                                                  int N, int E) {
    int lane = threadIdx.x & 63;
    int q    = lane >> 4;       // subgroup 0..3 -> node
    int sub  = lane & 15;       // uint4 index within the 256B row
    int node = blockIdx.x * 16 + (threadIdx.x >> 6) * 4 + q;
    if (node >= N) return;
    int beg = row_ptr[node];
    int end = row_ptr[node + 1];
    float a0 = 0.f, a1 = 0.f, a2 = 0.f, a3 = 0.f;
    float a4 = 0.f, a5 = 0.f, a6 = 0.f, a7 = 0.f;
    int e = beg;
    // peel to 16B alignment of the record stream
    int pre = min((4 - (beg & 3)) & 3, end - beg);
    for (int i = 0; i < pre; ++i, ++e) AGG_EDGE(s_edge[e]);
    // main: 8 edges per iter, records via two aligned uint4 loads
    for (; e + 8 <= end; e += 8) {
        uint4 ra = *(const uint4*)(s_edge + e);
        uint4 rb = *(const uint4*)(s_edge + e + 4);
        int k0 = (int)(ra.x & 0xffffu), k1 = (int)(ra.y & 0xffffu);
        int k2 = (int)(ra.z & 0xffffu), k3 = (int)(ra.w & 0xffffu);
        int k4 = (int)(rb.x & 0xffffu), k5 = (int)(rb.y & 0xffffu);
        int k6 = (int)(rb.z & 0xffffu), k7 = (int)(rb.w & 0xffffu);
        uint4 v0 = h128[(size_t)k0 * 16 + sub];
        uint4 v1 = h128[(size_t)k1 * 16 + sub];
        uint4 v2 = h128[(size_t)k2 * 16 + sub];
        uint4 v3 = h128[(size_t)k3 * 16 + sub];
        uint4 v4 = h128[(size_t)k4 * 16 + sub];
        uint4 v5 = h128[(size_t)k5 * 16 + sub];
        uint4 v6 = h128[(size_t)k6 * 16 + sub];
        uint4 v7 = h128[(size_t)k7 * 16 + sub];
        float w0 = bf2f((unsigned short)(ra.x >> 16));
        float w1 = bf2f((unsigned short)(ra.y >> 16));
        float w2 = bf2f((unsigned short)(ra.z >> 16));
        float w3 = bf2f((unsigned short)(ra.w >> 16));
        float w4 = bf2f((unsigned short)(rb.x >> 16));
        float w5 = bf2f((unsigned short)(rb.y >> 16));
        float w6 = bf2f((unsigned short)(rb.z >> 16));
        float w7 = bf2f((unsigned short)(rb.w >> 16));
#define ACC8(W, V)                                                        \
        a0 += W * bf2f((unsigned short)(V.x & 0xffffu));                  \
        a1 += W * bf2f((unsigned short)(V.x >> 16));                      \
        a2 += W * bf2f((unsigned short)(V.y & 0xffffu));                  \
        a3 += W * bf2f((unsigned short)(V.y >> 16));                      \
        a4 += W * bf2f((unsigned short)(V.z & 0xffffu));                  \
        a5 += W * bf2f((unsigned short)(V.z >> 16));                      \
        a6 += W * bf2f((unsigned short)(V.w & 0xffffu));                  \
        a7 += W * bf2f((unsigned short)(V.w >> 16));
        ACC8(w0, v0) ACC8(w1, v1) ACC8(w2, v2) ACC8(w3, v3)
        ACC8(w4, v4) ACC8(w5, v5) ACC8(w6, v6) ACC8(w7, v7)
#undef ACC8
    }
    // 4-edge tier
    for (; e + 4 <= end; e += 4) {
        uint4 ra = *(const uint4*)(s_edge + e);
        AGG_EDGE(ra.x); AGG_EDGE(ra.y); AGG_EDGE(ra.z); AGG_EDGE(ra.w);
    }
    for (; e < end; ++e) AGG_EDGE(s_edge[e]);
    float inv = (end > beg) ? 1.0f / (float)(end - beg) : 0.f;
    uint4 o;
    o.x = pack2(a0 * inv, a1 * inv);
    o.y = pack2(a2 * inv, a3 * inv);
    o.z = pack2(a4 * inv, a5 * inv);
    o.w = pack2(a6 * inv, a7 * inv);
    out128[(size_t)node * 16 + sub] = o;
}

// ---- fused SAGE linear: out = h @ Wself^T + b + neigh @ Wneigh^T (+relu)
// MFMA 16x16x32 bf16. W0|W1 staged in LDS (row stride 68 uints = 272B).
// Block = 4 waves; each wave computes 32 rows x 128 cols.
// A frag: lane holds A[m=lane&15][k=quad*8+j]; B frag: W[n=lane&15][k=quad*8+j]
// C/D: D[row=quad*4+r][col=lane&15]

#define WROW 68   // uints per W row in LDS (64 data + 4 pad)

__global__ __launch_bounds__(256) void gemm_layer(const unsigned short* __restrict__ A0,
                                                  const unsigned short* __restrict__ A1,
                                                  const unsigned short* __restrict__ W0,
                                                  const unsigned short* __restrict__ W1,
                                                  const unsigned short* __restrict__ bias,
                                                  void* __restrict__ out,
                                                  const unsigned int* __restrict__ emb32,
                                                  int n_rows, int relu, int is_final) {
    __shared__ unsigned int lw[2 * DIM * WROW];   // 69632 B
    int fp32_out = is_final ? block_flag(emb32) : (void(block_flag(emb32)), 0);
    int t = threadIdx.x;

    // stage W0|W1: each W is 2048 uint4-chunks, 16 chunks per 128-ushort row.
    // chunk c -> row = c>>4, uint offset = (c&15)*4.  8 chunks per thread.
#pragma unroll
    for (int mat = 0; mat < 2; ++mat) {
        const uint4* src = (const uint4*)(mat ? W1 : W0);
        unsigned int* dstl = lw + mat * DIM * WROW;
#pragma unroll
        for (int i = 0; i < 8; ++i) {
            int c = i * 256 + t;
            uint4 v = src[c];
            *(uint4*)&dstl[(c >> 4) * WROW + (c & 15) * 4] = v;
        }
    }
    __syncthreads();

    int wave = t >> 6;
    int lane = t & 63;
    int quad = lane >> 4;
    int l16  = lane & 15;
    int m_base = blockIdx.x * 128 + wave * 32;

    floatx4 acc0[8], acc1[8];
#pragma unroll
    for (int c = 0; c < 8; ++c) {
        acc0[c] = (floatx4){0.f, 0.f, 0.f, 0.f};
        acc1[c] = (floatx4){0.f, 0.f, 0.f, 0.f};
    }

    int r0 = min(m_base + l16, n_rows - 1);        // clamp; stores guarded
    int r1 = min(m_base + 16 + l16, n_rows - 1);

#pragma unroll
    for (int mat = 0; mat < 2; ++mat) {
        const unsigned short* A  = mat ? A1 : A0;
        const unsigned int* lwm = lw + mat * DIM * WROW;
        const unsigned short* Ar0 = A + (size_t)r0 * DIM;
        const unsigned short* Ar1 = A + (size_t)r1 * DIM;
#pragma unroll
        for (int ks = 0; ks < 4; ++ks) {
            int k0 = ks * 32 + quad * 8;
            bf16x8 a0 = *(const bf16x8*)(Ar0 + k0);
            bf16x8 a1 = *(const bf16x8*)(Ar1 + k0);
#pragma unroll
            for (int c = 0; c < 8; ++c) {
                bf16x8 b = *(const bf16x8*)&lwm[(c * 16 + l16) * WROW + (k0 >> 1)];
                acc0[c] = __builtin_amdgcn_mfma_f32_16x16x32_bf16(a0, b, acc0[c], 0, 0, 0);
                acc1[c] = __builtin_amdgcn_mfma_f32_16x16x32_bf16(a1, b, acc1[c], 0, 0, 0);
            }
        }
    }

#pragma unroll
    for (int c = 0; c < 8; ++c) {
        int col = c * 16 + l16;
        float bv = bf2f(bias[col]);
#pragma unroll
        for (int r = 0; r < 4; ++r) {
            int row0 = m_base + quad * 4 + r;
            int row1 = row0 + 16;
            if (row0 < n_rows) {
                float v = acc0[c][r] + bv;
                if (relu) v = fmaxf(v, 0.f);
                size_t idx = (size_t)row0 * DIM + col;
                if (fp32_out) ((float*)out)[idx] = v;
                else          ((unsigned short*)out)[idx] = f2bf(v);
            }
            if (row1 < n_rows) {
                float v = acc1[c][r] + bv;
                if (relu) v = fmaxf(v, 0.f);
                size_t idx = (size_t)row1 * DIM + col;
                if (fp32_out) ((float*)out)[idx] = v;
                else          ((unsigned short*)out)[idx] = f2bf(v);
            }
        }
    }
}

// ---- launch ------------------------------------------------------------

extern "C" void kernel_launch(void* const* d_in, const int* in_sizes, int n_in,
                              void* d_out, int out_size, void* d_ws, size_t ws_size,
                              hipStream_t stream) {
    const int* node_ids = (const int*)d_in[0];
    const int* edge_src = (const int*)d_in[1];
    const int* edge_dst = (const int*)d_in[2];
    const void* edge_w  = d_in[3];
    const void* emb     = d_in[4];
    const void* Ws1     = d_in[5];
    const void* Wn1     = d_in[6];
    const void* b1      = d_in[7];
    const void* Ws2     = d_in[8];
    const void* Wn2     = d_in[9];
    const void* b2      = d_in[10];

    const int N = in_sizes[0];
    const int E = in_sizes[1];
    const int NB = (N + 255) >> 8;   // <= 256 since N <= 65536

    char* w = (char*)d_ws;
    auto alloc = [&](size_t bytes) {
        char* p = w;
        w += (bytes + 255) & ~(size_t)255;
        return p;
    };
    int* bcnt           = (int*)alloc((size_t)256 * NB * 4);
    int* boff           = (int*)alloc((size_t)256 * NB * 4);
    int* btot           = (int*)alloc((size_t)256 * 4);
    int* row_ptr        = (int*)alloc((size_t)(N + 1) * 4);
    const int W = DIM * DIM;
    unsigned short* wcat = (unsigned short*)alloc((size_t)(4 * W + 2 * DIM) * 2);
    unsigned short* Ws1c = wcat;
    unsigned short* Wn1c = wcat + W;
    unsigned short* Ws2c = wcat + 2 * W;
    unsigned short* Wn2c = wcat + 3 * W;
    unsigned short* b1c  = wcat + 4 * W;
    unsigned short* b2c  = wcat + 4 * W + DIM;
    unsigned int* s_tmp  = (unsigned int*)alloc((size_t)E * 4);
    unsigned char* s_tmpb = (unsigned char*)alloc((size_t)E);
    unsigned int* s_edge = (unsigned int*)alloc((size_t)E * 4);
    unsigned short* h0  = (unsigned short*)alloc((size_t)N * DIM * 2);
    unsigned short* h1  = (unsigned short*)alloc((size_t)N * DIM * 2);
    unsigned short* ngh = (unsigned short*)alloc((size_t)N * DIM * 2);

    const unsigned int* emb32 = (const unsigned int*)emb;

    const int CN = 4 * W + 2 * DIM;
    const int conv_blocks = (CN + 255) / 256;
    const int gather_total4 = N * 16;                // uint4 units
    const int gather_blocks = (gather_total4 + 255) / 256;

    // hist ∥ prep, then scan -> scatter -> csr
    hist_prep_kernel<<<256 + conv_blocks + gather_blocks, 256, 0, stream>>>(
        edge_dst, bcnt, E, NB,
        Ws1, Wn1, Ws2, Wn2, b1, b2, wcat, node_ids, emb,
        (uint4*)h0, conv_blocks, gather_total4);
    bucket_scan<<<NB, 256, 0, stream>>>(bcnt, boff, btot, NB);
    bucket_scatter<<<256, 256, 0, stream>>>(edge_src, edge_dst, edge_w, emb32,
                                            boff, btot, s_tmp, s_tmpb, E, NB);
    bucket_csr<<<NB, 256, 0, stream>>>(btot, s_tmp, s_tmpb, s_edge, row_ptr, N, NB);

    // Layer 1
    agg_kernel<<<(N + 15) / 16, 256, 0, stream>>>((const uint4*)h0, row_ptr,
                                                  s_edge, (uint4*)ngh, N, E);
    gemm_layer<<<(N + 127) / 128, 256, 0, stream>>>(h0, ngh, Ws1c, Wn1c, b1c,
                                                    h1, emb32, N, 1, 0);

    // Layer 2
    agg_kernel<<<(N + 15) / 16, 256, 0, stream>>>((const uint4*)h1, row_ptr,
                                                  s_edge, (uint4*)ngh, N, E);
    gemm_layer<<<(N + 127) / 128, 256, 0, stream>>>(h1, ngh, Ws2c, Wn2c, b2c,
                                                    d_out, emb32, N, 0, 1);
}